// Round 2
// baseline (9415.327 us; speedup 1.0000x reference)
//
#include <hip/hip_runtime.h>
#include <hip/hip_bf16.h>

#define MF 24      // input feature dim
#define HIDF 32    // hidden dim
#define OUTF 16    // emb dim
#define ZDIM 88    // 3*MF + OUTF

union bf16x8 {
    float4 v;
    __hip_bfloat16 h[8];
};

// flagged scalar load: element i of a float array that is either bf16 or fp32
__device__ __forceinline__ float ldw(const void* p, int i, bool bf16) {
    return bf16 ? __bfloat162float(((const __hip_bfloat16*)p)[i])
                : ((const float*)p)[i];
}

// ---------------------------------------------------------------------------
// Detect input dtypes at runtime (deterministic, runs every launch).
// flags[0]=1 if float arrays are bf16-packed; flags[1]=1 if edge ints are i64.
// x_bin values are exactly {0,1}: a bf16 pair word has low-half 0x3F80 with
// p=1/2; an fp32 {0,1} word never does. int64 edges (ids < 2^31) have all
// odd 32-bit words == 0; int32 edge words are node ids (==0 w.p. 1e-5).
// ---------------------------------------------------------------------------
__global__ __launch_bounds__(64) void k_detect(const unsigned int* __restrict__ xw,
                                               const unsigned int* __restrict__ ew,
                                               int* __restrict__ flags) {
    if (blockIdx.x == 0 && threadIdx.x == 0) {
        int bf = 0;
        for (int k = 0; k < 64; ++k)
            if ((xw[k] & 0xFFFFu) == 0x3F80u) bf = 1;
        int zc = 0;
        for (int k = 0; k < 64; ++k)
            if (ew[2 * k + 1] == 0u) zc++;
        flags[0] = bf;
        flags[1] = (zc >= 32) ? 1 : 0;
    }
}

// ---------------------------------------------------------------------------
// Kernel 1: per-edge scatter of x rows into sums[col] (stride MF) + degree.
// ---------------------------------------------------------------------------
__global__ __launch_bounds__(256) void k_scatter_x(
    const void* __restrict__ x, const int* __restrict__ ei,
    const int* __restrict__ flags, float* __restrict__ deg,
    float* __restrict__ sums, int nE, int N) {
    const bool bf16 = flags[0] != 0;
    const bool i64 = flags[1] != 0;
    int e = blockIdx.x * 256 + threadIdx.x;
    if (e >= nE) return;
    int r = i64 ? ei[2 * (size_t)e] : ei[e];
    int c = i64 ? ei[2 * ((size_t)nE + e)] : ei[(size_t)nE + e];
    if ((unsigned)r >= (unsigned)N || (unsigned)c >= (unsigned)N) return;

    float xv[MF];
    if (bf16) {
        const float4* xr = reinterpret_cast<const float4*>(
            (const __hip_bfloat16*)x + (size_t)r * MF);
        bf16x8 u;
#pragma unroll
        for (int q = 0; q < 3; ++q) {
            u.v = xr[q];
#pragma unroll
            for (int i = 0; i < 8; ++i) xv[q * 8 + i] = __bfloat162float(u.h[i]);
        }
    } else {
        const float4* xr = reinterpret_cast<const float4*>(
            (const float*)x + (size_t)r * MF);
#pragma unroll
        for (int q = 0; q < 6; ++q) {
            float4 v = xr[q];
            xv[q * 4 + 0] = v.x; xv[q * 4 + 1] = v.y;
            xv[q * 4 + 2] = v.z; xv[q * 4 + 3] = v.w;
        }
    }
    atomicAdd(deg + c, 1.0f);
    float* s = sums + (size_t)c * MF;
#pragma unroll
    for (int i = 0; i < MF; ++i) atomicAdd(s + i, xv[i]);
}

// ---------------------------------------------------------------------------
// Kernel 2: per-node. frac1 = sums/max(deg,1); write z cols [0,72);
// h = relu(frac1 @ w1l.T + b1 + x @ w1r.T), stored bf16 in workspace.
// ---------------------------------------------------------------------------
__global__ __launch_bounds__(256) void k_node1(
    const void* __restrict__ x, const float* __restrict__ deg,
    const float* __restrict__ sums, __hip_bfloat16* __restrict__ h,
    void* __restrict__ out, const int* __restrict__ flags,
    const void* __restrict__ w1l, const void* __restrict__ b1,
    const void* __restrict__ w1r, int N) {
    const bool bf16 = flags[0] != 0;
    __shared__ float swl[HIDF * MF];
    __shared__ float swr[HIDF * MF];
    __shared__ float sb[HIDF];
    for (int i = threadIdx.x; i < HIDF * MF; i += 256) {
        swl[i] = ldw(w1l, i, bf16);
        swr[i] = ldw(w1r, i, bf16);
    }
    if (threadIdx.x < HIDF) sb[threadIdx.x] = ldw(b1, threadIdx.x, bf16);
    __syncthreads();

    int n = blockIdx.x * 256 + threadIdx.x;
    if (n >= N) return;

    float inv = 1.0f / fmaxf(deg[n], 1.0f);

    float xv[MF], fv[MF];
#pragma unroll
    for (int f = 0; f < MF; ++f) xv[f] = ldw(x, n * MF + f, bf16);
    const float* s = sums + (size_t)n * MF;
#pragma unroll
    for (int f = 0; f < MF; ++f) fv[f] = s[f] * inv;

    if (bf16) {
        __hip_bfloat16* z = (__hip_bfloat16*)out + N + (size_t)n * ZDIM;
#pragma unroll
        for (int f = 0; f < MF; ++f) {
            z[f] = __float2bfloat16(xv[f]);
            z[MF + f] = __float2bfloat16(fv[f]);
            z[2 * MF + f] = __float2bfloat16(xv[f] * fv[f]);
        }
    } else {
        float* z = (float*)out + N + (size_t)n * ZDIM;
#pragma unroll
        for (int f = 0; f < MF; ++f) {
            z[f] = xv[f];
            z[MF + f] = fv[f];
            z[2 * MF + f] = xv[f] * fv[f];
        }
    }

    __hip_bfloat16* hn = h + (size_t)n * HIDF;
#pragma unroll
    for (int j = 0; j < HIDF; ++j) {
        float acc = sb[j];
        const float* wl = swl + j * MF;
        const float* wr = swr + j * MF;
#pragma unroll
        for (int k = 0; k < MF; ++k) acc += fv[k] * wl[k] + xv[k] * wr[k];
        hn[j] = __float2bfloat16(fmaxf(acc, 0.0f));
    }
}

// ---------------------------------------------------------------------------
// Kernel 3: per-edge scatter of h rows (bf16) into sums[col] (stride HIDF).
// ---------------------------------------------------------------------------
__global__ __launch_bounds__(256) void k_scatter_h(
    const __hip_bfloat16* __restrict__ h, const int* __restrict__ ei,
    const int* __restrict__ flags, float* __restrict__ sums, int nE, int N) {
    const bool i64 = flags[1] != 0;
    int e = blockIdx.x * 256 + threadIdx.x;
    if (e >= nE) return;
    int r = i64 ? ei[2 * (size_t)e] : ei[e];
    int c = i64 ? ei[2 * ((size_t)nE + e)] : ei[(size_t)nE + e];
    if ((unsigned)r >= (unsigned)N || (unsigned)c >= (unsigned)N) return;

    const float4* hr = reinterpret_cast<const float4*>(h + (size_t)r * HIDF);
    float* s = sums + (size_t)c * HIDF;
    bf16x8 u;
#pragma unroll
    for (int q = 0; q < 4; ++q) {
        u.v = hr[q];
#pragma unroll
        for (int i = 0; i < 8; ++i)
            atomicAdd(s + q * 8 + i, __bfloat162float(u.h[i]));
    }
}

// ---------------------------------------------------------------------------
// Kernel 4: per-node. aggr2 = sums/max(deg,1);
// emb = relu(aggr2 @ w2l.T + b2 + h @ w2r.T); z cols [72,88);
// yhat = head_b + z . head_w  (z cols [0,72) re-read from out).
// ---------------------------------------------------------------------------
__global__ __launch_bounds__(256) void k_node2(
    const float* __restrict__ deg, const __hip_bfloat16* __restrict__ h,
    const float* __restrict__ sums, void* __restrict__ out,
    const int* __restrict__ flags,
    const void* __restrict__ w2l, const void* __restrict__ b2,
    const void* __restrict__ w2r, const void* __restrict__ head_w,
    const void* __restrict__ head_b, int N) {
    const bool bf16 = flags[0] != 0;
    __shared__ float swl[OUTF * HIDF];
    __shared__ float swr[OUTF * HIDF];
    __shared__ float sb2[OUTF];
    __shared__ float shw[ZDIM];
    __shared__ float shb;
    for (int i = threadIdx.x; i < OUTF * HIDF; i += 256) {
        swl[i] = ldw(w2l, i, bf16);
        swr[i] = ldw(w2r, i, bf16);
    }
    if (threadIdx.x < OUTF) sb2[threadIdx.x] = ldw(b2, threadIdx.x, bf16);
    if (threadIdx.x < ZDIM) shw[threadIdx.x] = ldw(head_w, threadIdx.x, bf16);
    if (threadIdx.x == 0) shb = ldw(head_b, 0, bf16);
    __syncthreads();

    int n = blockIdx.x * 256 + threadIdx.x;
    if (n >= N) return;

    float inv = 1.0f / fmaxf(deg[n], 1.0f);

    float hv[HIDF], ag[HIDF];
    const float4* hp = reinterpret_cast<const float4*>(h + (size_t)n * HIDF);
    const float4* sp = reinterpret_cast<const float4*>(sums + (size_t)n * HIDF);
    bf16x8 u;
#pragma unroll
    for (int q = 0; q < 4; ++q) {
        u.v = hp[q];
#pragma unroll
        for (int i = 0; i < 8; ++i) hv[q * 8 + i] = __bfloat162float(u.h[i]);
    }
#pragma unroll
    for (int q = 0; q < 8; ++q) {
        float4 b = sp[q];
        ag[q * 4 + 0] = b.x * inv; ag[q * 4 + 1] = b.y * inv;
        ag[q * 4 + 2] = b.z * inv; ag[q * 4 + 3] = b.w * inv;
    }

    float emb[OUTF];
#pragma unroll
    for (int o = 0; o < OUTF; ++o) {
        float acc = sb2[o];
        const float* wl = swl + o * HIDF;
        const float* wr = swr + o * HIDF;
#pragma unroll
        for (int j = 0; j < HIDF; ++j) acc += ag[j] * wl[j] + hv[j] * wr[j];
        emb[o] = fmaxf(acc, 0.0f);
    }

    float yacc = shb;
    if (bf16) {
        __hip_bfloat16* z = (__hip_bfloat16*)out + N + (size_t)n * ZDIM;
#pragma unroll
        for (int f = 0; f < 3 * MF; ++f) yacc += __bfloat162float(z[f]) * shw[f];
#pragma unroll
        for (int o = 0; o < OUTF; ++o) {
            z[3 * MF + o] = __float2bfloat16(emb[o]);
            yacc += emb[o] * shw[3 * MF + o];
        }
        ((__hip_bfloat16*)out)[n] = __float2bfloat16(yacc);
    } else {
        float* z = (float*)out + N + (size_t)n * ZDIM;
#pragma unroll
        for (int f = 0; f < 3 * MF; ++f) yacc += z[f] * shw[f];
#pragma unroll
        for (int o = 0; o < OUTF; ++o) {
            z[3 * MF + o] = emb[o];
            yacc += emb[o] * shw[3 * MF + o];
        }
        ((float*)out)[n] = yacc;
    }
}

extern "C" void kernel_launch(void* const* d_in, const int* in_sizes, int n_in,
                              void* d_out, int out_size, void* d_ws, size_t ws_size,
                              hipStream_t stream) {
    const void* x = d_in[0];
    const int* ei = (const int*)d_in[1];
    const void* w1l = d_in[2];
    const void* b1 = d_in[3];
    const void* w1r = d_in[4];
    const void* w2l = d_in[5];
    const void* b2 = d_in[6];
    const void* w2r = d_in[7];
    const void* head_w = d_in[8];
    const void* head_b = d_in[9];

    const int N = in_sizes[0] / MF;
    const int nE = in_sizes[1] / 2;

    // workspace: flags(256B) | deg[N] f32 | sums[32N] f32 (layer1: stride 24,
    // re-zeroed, layer2: stride 32) | h[32N] bf16
    const size_t need = 256 + (size_t)N * 4 + (size_t)N * HIDF * 4 + (size_t)N * HIDF * 2;
    if (ws_size < need) return;  // diagnostic: output stays zero (absmax ~1.06)

    int* flags = (int*)d_ws;
    float* deg = (float*)((char*)d_ws + 256);
    float* sums = deg + N;
    __hip_bfloat16* h = (__hip_bfloat16*)(sums + (size_t)N * HIDF);

    // zero flags+deg+sums
    hipMemsetAsync(d_ws, 0, 256 + (size_t)N * 4 + (size_t)N * HIDF * 4, stream);

    int ebBlocks = (nE + 255) / 256;
    int nbBlocks = (N + 255) / 256;
    k_detect<<<1, 64, 0, stream>>>((const unsigned int*)x, (const unsigned int*)ei,
                                   flags);
    k_scatter_x<<<ebBlocks, 256, 0, stream>>>(x, ei, flags, deg, sums, nE, N);
    k_node1<<<nbBlocks, 256, 0, stream>>>(x, deg, sums, h, d_out, flags,
                                          w1l, b1, w1r, N);
    // re-zero sums for layer 2 (stride 32)
    hipMemsetAsync(sums, 0, (size_t)N * HIDF * 4, stream);
    k_scatter_h<<<ebBlocks, 256, 0, stream>>>(h, ei, flags, sums, nE, N);
    k_node2<<<nbBlocks, 256, 0, stream>>>(deg, h, sums, d_out, flags,
                                          w2l, b2, w2r, head_w, head_b, N);
}

// Round 3
// 845.603 us; speedup vs baseline: 11.1345x; 11.1345x over previous
//
#include <hip/hip_runtime.h>
#include <hip/hip_bf16.h>

#define MF 24      // input feature dim
#define HIDF 32    // hidden dim
#define OUTF 16    // emb dim
#define ZDIM 88    // 3*MF + OUTF
#define NPB 8      // nodes per 256-thread block in gather kernels

// flagged scalar load: element i of a float array that is either bf16 or fp32
__device__ __forceinline__ float ldw(const void* p, size_t i, bool bf16) {
    return bf16 ? __bfloat162float(((const __hip_bfloat16*)p)[i])
                : ((const float*)p)[i];
}

// ---------------------------------------------------------------------------
// Detect input dtypes at runtime (deterministic, runs every launch).
// flags[0]=1 if float arrays are bf16-packed; flags[1]=1 if edge ints are i64.
// ---------------------------------------------------------------------------
__global__ __launch_bounds__(64) void k_detect(const unsigned int* __restrict__ xw,
                                               const unsigned int* __restrict__ ew,
                                               int* __restrict__ flags) {
    if (blockIdx.x == 0 && threadIdx.x == 0) {
        int bf = 0;
        for (int k = 0; k < 64; ++k)
            if ((xw[k] & 0xFFFFu) == 0x3F80u) bf = 1;
        int zc = 0;
        for (int k = 0; k < 64; ++k)
            if (ew[2 * k + 1] == 0u) zc++;
        flags[0] = bf;
        flags[1] = (zc >= 32) ? 1 : 0;
    }
}

// ---------------------------------------------------------------------------
// CSR build step 1: in-degree histogram (int atomics).
// ---------------------------------------------------------------------------
__global__ __launch_bounds__(256) void k_deg(const int* __restrict__ ei,
                                             const int* __restrict__ flags,
                                             int* __restrict__ degi, int nE, int N) {
    const bool i64 = flags[1] != 0;
    int e = blockIdx.x * 256 + threadIdx.x;
    if (e >= nE) return;
    int c = i64 ? ei[2 * ((size_t)nE + e)] : ei[(size_t)nE + e];
    if ((unsigned)c < (unsigned)N) atomicAdd(degi + c, 1);
}

// ---------------------------------------------------------------------------
// Exclusive scan of degi -> cur (start offsets), 3 kernels.
// ---------------------------------------------------------------------------
__global__ __launch_bounds__(256) void k_scan1(const int* __restrict__ degi,
                                               int* __restrict__ partials, int N) {
    __shared__ int red[256];
    int i = blockIdx.x * 256 + threadIdx.x;
    int t = threadIdx.x;
    red[t] = (i < N) ? degi[i] : 0;
    __syncthreads();
    for (int s = 128; s > 0; s >>= 1) {
        if (t < s) red[t] += red[t + s];
        __syncthreads();
    }
    if (t == 0) partials[blockIdx.x] = red[0];
}

__global__ __launch_bounds__(1024) void k_scan2(int* __restrict__ partials, int nB) {
    __shared__ int s[1024];
    int t = threadIdx.x;
    int v = (t < nB) ? partials[t] : 0;
    s[t] = v;
    __syncthreads();
    for (int off = 1; off < 1024; off <<= 1) {
        int y = (t >= off) ? s[t - off] : 0;
        __syncthreads();
        s[t] += y;
        __syncthreads();
    }
    if (t < nB) partials[t] = s[t] - v;  // exclusive
}

__global__ __launch_bounds__(256) void k_scan3(const int* __restrict__ degi,
                                               const int* __restrict__ partials,
                                               int* __restrict__ cur, int N) {
    __shared__ int s[256];
    int i = blockIdx.x * 256 + threadIdx.x;
    int t = threadIdx.x;
    int v = (i < N) ? degi[i] : 0;
    s[t] = v;
    __syncthreads();
    for (int off = 1; off < 256; off <<= 1) {
        int y = (t >= off) ? s[t - off] : 0;
        __syncthreads();
        s[t] += y;
        __syncthreads();
    }
    if (i < N) cur[i] = partials[blockIdx.x] + s[t] - v;  // start offset
}

// ---------------------------------------------------------------------------
// CSR build step 2: fill source lists. cur[c] is bumped to end offset;
// consumers recover start = cur[n] - degi[n].
// ---------------------------------------------------------------------------
__global__ __launch_bounds__(256) void k_fill(const int* __restrict__ ei,
                                              const int* __restrict__ flags,
                                              int* __restrict__ cur,
                                              int* __restrict__ srcs, int nE, int N) {
    const bool i64 = flags[1] != 0;
    int e = blockIdx.x * 256 + threadIdx.x;
    if (e >= nE) return;
    int r = i64 ? ei[2 * (size_t)e] : ei[e];
    int c = i64 ? ei[2 * ((size_t)nE + e)] : ei[(size_t)nE + e];
    if ((unsigned)r >= (unsigned)N || (unsigned)c >= (unsigned)N) return;
    int pos = atomicAdd(cur + c, 1);
    srcs[pos] = r;
}

// ---------------------------------------------------------------------------
// Layer 1 (fused gather + node math): 32 lanes per node, lane = feature.
// frac1 = mean of x[src]; z cols [0,72); h = relu(frac1 W1l^T + b1 + x W1r^T).
// LDS weight strides padded (24->25) to stay bank-conflict-free.
// ---------------------------------------------------------------------------
__global__ __launch_bounds__(256) void k_layer1(
    const void* __restrict__ x, const int* __restrict__ degi,
    const int* __restrict__ cur, const int* __restrict__ srcs,
    __hip_bfloat16* __restrict__ h, void* __restrict__ out,
    const int* __restrict__ flags,
    const void* __restrict__ w1l, const void* __restrict__ b1,
    const void* __restrict__ w1r, int N) {
    const bool bf16 = flags[0] != 0;
    __shared__ float swl[HIDF * 25];
    __shared__ float swr[HIDF * 25];
    __shared__ float sb[HIDF];
    __shared__ float xs[NPB][MF];
    __shared__ float fs[NPB][MF];
    for (int i = threadIdx.x; i < HIDF * MF; i += 256) {
        int j = i / MF, k = i - j * MF;
        swl[j * 25 + k] = ldw(w1l, i, bf16);
        swr[j * 25 + k] = ldw(w1r, i, bf16);
    }
    if (threadIdx.x < HIDF) sb[threadIdx.x] = ldw(b1, threadIdx.x, bf16);
    __syncthreads();

    int lane = threadIdx.x & 31;
    int g = threadIdx.x >> 5;
    int node = blockIdx.x * NPB + g;
    bool valid = node < N;

    int dg = 0, p0 = 0;
    if (valid) {
        dg = degi[node];
        p0 = cur[node] - dg;  // cur was bumped to end by k_fill
    }
    float sum = 0.f, xv = 0.f;
    if (valid && lane < MF) {
        xv = ldw(x, (size_t)node * MF + lane, bf16);
        for (int e = 0; e < dg; ++e) {
            int s = srcs[p0 + e];
            sum += ldw(x, (size_t)s * MF + lane, bf16);
        }
    }
    float inv = 1.f / fmaxf((float)dg, 1.f);
    float fv = sum * inv;
    if (valid && lane < MF) {
        if (bf16) {
            __hip_bfloat16* z = (__hip_bfloat16*)out + N + (size_t)node * ZDIM;
            z[lane] = __float2bfloat16(xv);
            z[MF + lane] = __float2bfloat16(fv);
            z[2 * MF + lane] = __float2bfloat16(xv * fv);
        } else {
            float* z = (float*)out + N + (size_t)node * ZDIM;
            z[lane] = xv;
            z[MF + lane] = fv;
            z[2 * MF + lane] = xv * fv;
        }
        xs[g][lane] = xv;
        fs[g][lane] = fv;
    }
    __syncthreads();
    if (valid) {
        float acc = sb[lane];
#pragma unroll
        for (int k = 0; k < MF; ++k)
            acc += fs[g][k] * swl[lane * 25 + k] + xs[g][k] * swr[lane * 25 + k];
        h[(size_t)node * HIDF + lane] = __float2bfloat16(fmaxf(acc, 0.f));
    }
}

// ---------------------------------------------------------------------------
// Layer 2 (fused gather + node math + head): 32 lanes per node.
// aggr2 = mean of h[src]; emb = relu(aggr2 W2l^T + b2 + h W2r^T); z[72:88);
// yhat = head_b + z . head_w  (z[0:72) re-read from out, emb from LDS).
// ---------------------------------------------------------------------------
__global__ __launch_bounds__(256) void k_layer2(
    const int* __restrict__ degi, const int* __restrict__ cur,
    const int* __restrict__ srcs, const __hip_bfloat16* __restrict__ h,
    void* __restrict__ out, const int* __restrict__ flags,
    const void* __restrict__ w2l, const void* __restrict__ b2,
    const void* __restrict__ w2r, const void* __restrict__ head_w,
    const void* __restrict__ head_b, int N) {
    const bool bf16 = flags[0] != 0;
    __shared__ float swl[OUTF * 33];
    __shared__ float swr[OUTF * 33];
    __shared__ float sb2[OUTF];
    __shared__ float shw[ZDIM];
    __shared__ float shb;
    __shared__ float ags[NPB][HIDF];
    __shared__ float hvs[NPB][HIDF];
    __shared__ float embs[NPB][OUTF];
    for (int i = threadIdx.x; i < OUTF * HIDF; i += 256) {
        int o = i >> 5, j = i & 31;
        swl[o * 33 + j] = ldw(w2l, i, bf16);
        swr[o * 33 + j] = ldw(w2r, i, bf16);
    }
    if (threadIdx.x < OUTF) sb2[threadIdx.x] = ldw(b2, threadIdx.x, bf16);
    if (threadIdx.x < ZDIM) shw[threadIdx.x] = ldw(head_w, threadIdx.x, bf16);
    if (threadIdx.x == 0) shb = ldw(head_b, 0, bf16);
    __syncthreads();

    int lane = threadIdx.x & 31;
    int g = threadIdx.x >> 5;
    int node = blockIdx.x * NPB + g;
    bool valid = node < N;

    int dg = 0, p0 = 0;
    if (valid) {
        dg = degi[node];
        p0 = cur[node] - dg;
    }
    float sum = 0.f;
    if (valid) {
        float hv = __bfloat162float(h[(size_t)node * HIDF + lane]);
        for (int e = 0; e < dg; ++e) {
            int s = srcs[p0 + e];
            sum += __bfloat162float(h[(size_t)s * HIDF + lane]);
        }
        float inv = 1.f / fmaxf((float)dg, 1.f);
        ags[g][lane] = sum * inv;
        hvs[g][lane] = hv;
    }
    __syncthreads();
    if (valid && lane < OUTF) {
        float acc = sb2[lane];
#pragma unroll
        for (int j = 0; j < HIDF; ++j)
            acc += ags[g][j] * swl[lane * 33 + j] + hvs[g][j] * swr[lane * 33 + j];
        acc = fmaxf(acc, 0.f);
        embs[g][lane] = acc;
        if (bf16)
            ((__hip_bfloat16*)out + N + (size_t)node * ZDIM)[3 * MF + lane] =
                __float2bfloat16(acc);
        else
            ((float*)out + N + (size_t)node * ZDIM)[3 * MF + lane] = acc;
    }
    __syncthreads();

    float part = 0.f;
    if (valid) {
        size_t zb = (size_t)N + (size_t)node * ZDIM;
        float z0 = bf16 ? __bfloat162float(((const __hip_bfloat16*)out)[zb + lane])
                        : ((const float*)out)[zb + lane];
        part += z0 * shw[lane];
        float z1 = bf16 ? __bfloat162float(((const __hip_bfloat16*)out)[zb + lane + 32])
                        : ((const float*)out)[zb + lane + 32];
        part += z1 * shw[lane + 32];
        int f2 = lane + 64;
        if (f2 < 3 * MF) {
            float z2 = bf16 ? __bfloat162float(((const __hip_bfloat16*)out)[zb + f2])
                            : ((const float*)out)[zb + f2];
            part += z2 * shw[f2];
        } else if (f2 < ZDIM) {
            part += embs[g][f2 - 3 * MF] * shw[f2];
        }
    }
#pragma unroll
    for (int off = 16; off > 0; off >>= 1) part += __shfl_down(part, off, 32);
    if (valid && lane == 0) {
        float y = part + shb;
        if (bf16) ((__hip_bfloat16*)out)[node] = __float2bfloat16(y);
        else ((float*)out)[node] = y;
    }
}

extern "C" void kernel_launch(void* const* d_in, const int* in_sizes, int n_in,
                              void* d_out, int out_size, void* d_ws, size_t ws_size,
                              hipStream_t stream) {
    const void* x = d_in[0];
    const int* ei = (const int*)d_in[1];
    const void* w1l = d_in[2];
    const void* b1 = d_in[3];
    const void* w1r = d_in[4];
    const void* w2l = d_in[5];
    const void* b2 = d_in[6];
    const void* w2r = d_in[7];
    const void* head_w = d_in[8];
    const void* head_b = d_in[9];

    const int N = in_sizes[0] / MF;
    const int nE = in_sizes[1] / 2;
    const int nB = (N + 255) / 256;

    // workspace: flags(256B) | degi[N] | cur[N] | partials[1024] | srcs[nE]
    //            | h[N*32] bf16
    int* flags = (int*)d_ws;
    int* degi = (int*)((char*)d_ws + 256);
    int* cur = degi + N;
    int* partials = cur + N;
    int* srcs = partials + 1024;
    __hip_bfloat16* h = (__hip_bfloat16*)(srcs + nE);

    const size_t need = 256 + ((size_t)2 * N + 1024 + nE) * 4 + (size_t)N * HIDF * 2;
    if (ws_size < need || nB > 1024) return;  // visible failure (zero output)

    hipMemsetAsync(degi, 0, (size_t)N * 4, stream);

    const int eb = (nE + 255) / 256;
    const int gb = (N + NPB - 1) / NPB;
    k_detect<<<1, 64, 0, stream>>>((const unsigned int*)x, (const unsigned int*)ei, flags);
    k_deg<<<eb, 256, 0, stream>>>(ei, flags, degi, nE, N);
    k_scan1<<<nB, 256, 0, stream>>>(degi, partials, N);
    k_scan2<<<1, 1024, 0, stream>>>(partials, nB);
    k_scan3<<<nB, 256, 0, stream>>>(degi, partials, cur, N);
    k_fill<<<eb, 256, 0, stream>>>(ei, flags, cur, srcs, nE, N);
    k_layer1<<<gb, 256, 0, stream>>>(x, degi, cur, srcs, h, d_out, flags,
                                     w1l, b1, w1r, N);
    k_layer2<<<gb, 256, 0, stream>>>(degi, cur, srcs, h, d_out, flags,
                                     w2l, b2, w2r, head_w, head_b, N);
}

// Round 4
// 576.397 us; speedup vs baseline: 16.3348x; 1.4670x over previous
//
#include <hip/hip_runtime.h>
#include <hip/hip_bf16.h>

#define MF 24      // input feature dim
#define HIDF 32    // hidden dim
#define OUTF 16    // emb dim
#define ZDIM 88    // 3*MF + OUTF
#define NPB 8      // nodes per 256-thread block in gather kernels

union bf16x8 {
    float4 v;
    __hip_bfloat16 h[8];
};

// flagged scalar load: element i of a float array that is either bf16 or fp32
__device__ __forceinline__ float ldw(const void* p, size_t i, bool bf16) {
    return bf16 ? __bfloat162float(((const __hip_bfloat16*)p)[i])
                : ((const float*)p)[i];
}

// ---------------------------------------------------------------------------
// Detect input dtypes at runtime (deterministic, runs every launch).
// flags[0]=1 if float arrays are bf16-packed; flags[1]=1 if edge ints are i64.
// ---------------------------------------------------------------------------
__global__ __launch_bounds__(64) void k_detect(const unsigned int* __restrict__ xw,
                                               const unsigned int* __restrict__ ew,
                                               int* __restrict__ flags) {
    if (blockIdx.x == 0 && threadIdx.x == 0) {
        int bf = 0;
        for (int k = 0; k < 64; ++k)
            if ((xw[k] & 0xFFFFu) == 0x3F80u) bf = 1;
        int zc = 0;
        for (int k = 0; k < 64; ++k)
            if (ew[2 * k + 1] == 0u) zc++;
        flags[0] = bf;
        flags[1] = (zc >= 32) ? 1 : 0;
    }
}

// ---------------------------------------------------------------------------
// Pack binary x rows (24 wide) into u32 bitmasks. x values are exactly {0,1}.
// ---------------------------------------------------------------------------
__global__ __launch_bounds__(256) void k_pack(const void* __restrict__ x,
                                              const int* __restrict__ flags,
                                              unsigned int* __restrict__ xpack, int N) {
    const bool bf16 = flags[0] != 0;
    int n = blockIdx.x * 256 + threadIdx.x;
    if (n >= N) return;
    unsigned int m = 0;
    if (bf16) {
        const float4* xr = reinterpret_cast<const float4*>(
            (const __hip_bfloat16*)x + (size_t)n * MF);
        bf16x8 u;
#pragma unroll
        for (int q = 0; q < 3; ++q) {
            u.v = xr[q];
#pragma unroll
            for (int i = 0; i < 8; ++i)
                if (__bfloat162float(u.h[i]) != 0.f) m |= 1u << (q * 8 + i);
        }
    } else {
        const float* xr = (const float*)x + (size_t)n * MF;
#pragma unroll
        for (int k = 0; k < MF; ++k)
            if (xr[k] != 0.f) m |= 1u << k;
    }
    xpack[n] = m;
}

// ---------------------------------------------------------------------------
// CSR build step 1: in-degree histogram, 4 edges per thread.
// ---------------------------------------------------------------------------
__global__ __launch_bounds__(256) void k_deg(const int* __restrict__ ei,
                                             const int* __restrict__ flags,
                                             int* __restrict__ degi, int nE, int N) {
    const bool i64 = flags[1] != 0;
    int base = (blockIdx.x * 256 + threadIdx.x) * 4;
#pragma unroll
    for (int i = 0; i < 4; ++i) {
        int e = base + i;
        if (e < nE) {
            int c = i64 ? ei[2 * ((size_t)nE + e)] : ei[(size_t)nE + e];
            if ((unsigned)c < (unsigned)N) atomicAdd(degi + c, 1);
        }
    }
}

// ---------------------------------------------------------------------------
// Exclusive scan of degi -> cur (start offsets), 3 kernels.
// ---------------------------------------------------------------------------
__global__ __launch_bounds__(256) void k_scan1(const int* __restrict__ degi,
                                               int* __restrict__ partials, int N) {
    __shared__ int red[256];
    int i = blockIdx.x * 256 + threadIdx.x;
    int t = threadIdx.x;
    red[t] = (i < N) ? degi[i] : 0;
    __syncthreads();
    for (int s = 128; s > 0; s >>= 1) {
        if (t < s) red[t] += red[t + s];
        __syncthreads();
    }
    if (t == 0) partials[blockIdx.x] = red[0];
}

__global__ __launch_bounds__(1024) void k_scan2(int* __restrict__ partials, int nB) {
    __shared__ int s[1024];
    int t = threadIdx.x;
    int v = (t < nB) ? partials[t] : 0;
    s[t] = v;
    __syncthreads();
    for (int off = 1; off < 1024; off <<= 1) {
        int y = (t >= off) ? s[t - off] : 0;
        __syncthreads();
        s[t] += y;
        __syncthreads();
    }
    if (t < nB) partials[t] = s[t] - v;  // exclusive
}

__global__ __launch_bounds__(256) void k_scan3(const int* __restrict__ degi,
                                               const int* __restrict__ partials,
                                               int* __restrict__ cur, int N) {
    __shared__ int s[256];
    int i = blockIdx.x * 256 + threadIdx.x;
    int t = threadIdx.x;
    int v = (i < N) ? degi[i] : 0;
    s[t] = v;
    __syncthreads();
    for (int off = 1; off < 256; off <<= 1) {
        int y = (t >= off) ? s[t - off] : 0;
        __syncthreads();
        s[t] += y;
        __syncthreads();
    }
    if (i < N) cur[i] = partials[blockIdx.x] + s[t] - v;  // start offset
}

// ---------------------------------------------------------------------------
// CSR build step 2: fill source lists, 4 edges per thread. cur[c] is bumped
// to end offset; consumers recover start = cur[n] - degi[n].
// ---------------------------------------------------------------------------
__global__ __launch_bounds__(256) void k_fill(const int* __restrict__ ei,
                                              const int* __restrict__ flags,
                                              int* __restrict__ cur,
                                              int* __restrict__ srcs, int nE, int N) {
    const bool i64 = flags[1] != 0;
    int base = (blockIdx.x * 256 + threadIdx.x) * 4;
#pragma unroll
    for (int i = 0; i < 4; ++i) {
        int e = base + i;
        if (e < nE) {
            int r = i64 ? ei[2 * (size_t)e] : ei[e];
            int c = i64 ? ei[2 * ((size_t)nE + e)] : ei[(size_t)nE + e];
            if ((unsigned)r < (unsigned)N && (unsigned)c < (unsigned)N) {
                int pos = atomicAdd(cur + c, 1);
                srcs[pos] = r;
            }
        }
    }
}

// ---------------------------------------------------------------------------
// Layer 1 (bit-packed gather + node math): 32 lanes per node.
// cnt[lane] = #neighbors with bit `lane`; frac1 = cnt/deg (exact ints).
// z cols [0,72); h = relu(frac1 W1l^T + b1 + x W1r^T) via shfl + LDS weights.
// ---------------------------------------------------------------------------
__global__ __launch_bounds__(256) void k_layer1(
    const unsigned int* __restrict__ xpack, const int* __restrict__ degi,
    const int* __restrict__ cur, const int* __restrict__ srcs,
    __hip_bfloat16* __restrict__ h, void* __restrict__ out,
    const int* __restrict__ flags,
    const void* __restrict__ w1l, const void* __restrict__ b1,
    const void* __restrict__ w1r, int N) {
    const bool bf16 = flags[0] != 0;
    __shared__ float swl[HIDF * 25];  // stride 25: conflict-free for lane*25+k
    __shared__ float swr[HIDF * 25];
    __shared__ float sb[HIDF];
    for (int i = threadIdx.x; i < HIDF * MF; i += 256) {
        int j = i / MF, k = i - j * MF;
        swl[j * 25 + k] = ldw(w1l, i, bf16);
        swr[j * 25 + k] = ldw(w1r, i, bf16);
    }
    if (threadIdx.x < HIDF) sb[threadIdx.x] = ldw(b1, threadIdx.x, bf16);
    __syncthreads();

    int lane = threadIdx.x & 31;
    int g = threadIdx.x >> 5;
    int node = blockIdx.x * NPB + g;
    if (node >= N) return;  // no barriers below

    int dg = degi[node];
    int p0 = cur[node] - dg;
    unsigned int xpn = xpack[node];

    int cnt = 0;
    int e = 0;
    for (; e + 4 <= dg; e += 4) {
        unsigned int a0 = xpack[srcs[p0 + e]];
        unsigned int a1 = xpack[srcs[p0 + e + 1]];
        unsigned int a2 = xpack[srcs[p0 + e + 2]];
        unsigned int a3 = xpack[srcs[p0 + e + 3]];
        cnt += ((a0 >> lane) & 1) + ((a1 >> lane) & 1) +
               ((a2 >> lane) & 1) + ((a3 >> lane) & 1);
    }
    for (; e < dg; ++e) cnt += (xpack[srcs[p0 + e]] >> lane) & 1;

    float inv = 1.f / fmaxf((float)dg, 1.f);
    float fv = (float)cnt * inv;          // lanes >= 24: cnt==0 -> fv==0
    float xv = (float)((xpn >> lane) & 1);

    if (lane < MF) {
        if (bf16) {
            __hip_bfloat16* z = (__hip_bfloat16*)out + N + (size_t)node * ZDIM;
            z[lane] = __float2bfloat16(xv);
            z[MF + lane] = __float2bfloat16(fv);
            z[2 * MF + lane] = __float2bfloat16(xv * fv);
        } else {
            float* z = (float*)out + N + (size_t)node * ZDIM;
            z[lane] = xv;
            z[MF + lane] = fv;
            z[2 * MF + lane] = xv * fv;
        }
    }

    float acc = sb[lane];
#pragma unroll
    for (int k = 0; k < MF; ++k) {
        float fk = __shfl(fv, k, 32);
        float xk = (float)((xpn >> k) & 1);
        acc += fk * swl[lane * 25 + k] + xk * swr[lane * 25 + k];
    }
    h[(size_t)node * HIDF + lane] = __float2bfloat16(fmaxf(acc, 0.f));
}

// ---------------------------------------------------------------------------
// Layer 2 (fused gather + node math + head): 32 lanes per node, unroll-4
// gather. aggr2 = mean of h[src]; emb = relu(aggr2 W2l^T + b2 + h W2r^T);
// z[72:88); yhat = head_b + z . head_w.
// ---------------------------------------------------------------------------
__global__ __launch_bounds__(256) void k_layer2(
    const int* __restrict__ degi, const int* __restrict__ cur,
    const int* __restrict__ srcs, const __hip_bfloat16* __restrict__ h,
    void* __restrict__ out, const int* __restrict__ flags,
    const void* __restrict__ w2l, const void* __restrict__ b2,
    const void* __restrict__ w2r, const void* __restrict__ head_w,
    const void* __restrict__ head_b, int N) {
    const bool bf16 = flags[0] != 0;
    __shared__ float swl[OUTF * 33];
    __shared__ float swr[OUTF * 33];
    __shared__ float sb2[OUTF];
    __shared__ float shw[ZDIM];
    __shared__ float shb;
    __shared__ float ags[NPB][HIDF];
    __shared__ float hvs[NPB][HIDF];
    __shared__ float embs[NPB][OUTF];
    for (int i = threadIdx.x; i < OUTF * HIDF; i += 256) {
        int o = i >> 5, j = i & 31;
        swl[o * 33 + j] = ldw(w2l, i, bf16);
        swr[o * 33 + j] = ldw(w2r, i, bf16);
    }
    if (threadIdx.x < OUTF) sb2[threadIdx.x] = ldw(b2, threadIdx.x, bf16);
    if (threadIdx.x < ZDIM) shw[threadIdx.x] = ldw(head_w, threadIdx.x, bf16);
    if (threadIdx.x == 0) shb = ldw(head_b, 0, bf16);
    __syncthreads();

    int lane = threadIdx.x & 31;
    int g = threadIdx.x >> 5;
    int node = blockIdx.x * NPB + g;
    bool valid = node < N;

    int dg = 0, p0 = 0;
    if (valid) {
        dg = degi[node];
        p0 = cur[node] - dg;
    }
    float sum = 0.f;
    if (valid) {
        float hv = __bfloat162float(h[(size_t)node * HIDF + lane]);
        int e = 0;
        for (; e + 4 <= dg; e += 4) {
            int s0 = srcs[p0 + e], s1 = srcs[p0 + e + 1];
            int s2 = srcs[p0 + e + 2], s3 = srcs[p0 + e + 3];
            float v0 = __bfloat162float(h[(size_t)s0 * HIDF + lane]);
            float v1 = __bfloat162float(h[(size_t)s1 * HIDF + lane]);
            float v2 = __bfloat162float(h[(size_t)s2 * HIDF + lane]);
            float v3 = __bfloat162float(h[(size_t)s3 * HIDF + lane]);
            sum += (v0 + v1) + (v2 + v3);
        }
        for (; e < dg; ++e) {
            int s = srcs[p0 + e];
            sum += __bfloat162float(h[(size_t)s * HIDF + lane]);
        }
        float inv = 1.f / fmaxf((float)dg, 1.f);
        ags[g][lane] = sum * inv;
        hvs[g][lane] = hv;
    }
    __syncthreads();
    if (valid && lane < OUTF) {
        float acc = sb2[lane];
#pragma unroll
        for (int j = 0; j < HIDF; ++j)
            acc += ags[g][j] * swl[lane * 33 + j] + hvs[g][j] * swr[lane * 33 + j];
        acc = fmaxf(acc, 0.f);
        embs[g][lane] = acc;
        if (bf16)
            ((__hip_bfloat16*)out + N + (size_t)node * ZDIM)[3 * MF + lane] =
                __float2bfloat16(acc);
        else
            ((float*)out + N + (size_t)node * ZDIM)[3 * MF + lane] = acc;
    }
    __syncthreads();

    float part = 0.f;
    if (valid) {
        size_t zb = (size_t)N + (size_t)node * ZDIM;
        float z0 = bf16 ? __bfloat162float(((const __hip_bfloat16*)out)[zb + lane])
                        : ((const float*)out)[zb + lane];
        part += z0 * shw[lane];
        float z1 = bf16 ? __bfloat162float(((const __hip_bfloat16*)out)[zb + lane + 32])
                        : ((const float*)out)[zb + lane + 32];
        part += z1 * shw[lane + 32];
        int f2 = lane + 64;
        if (f2 < 3 * MF) {
            float z2 = bf16 ? __bfloat162float(((const __hip_bfloat16*)out)[zb + f2])
                            : ((const float*)out)[zb + f2];
            part += z2 * shw[f2];
        } else if (f2 < ZDIM) {
            part += embs[g][f2 - 3 * MF] * shw[f2];
        }
    }
#pragma unroll
    for (int off = 16; off > 0; off >>= 1) part += __shfl_down(part, off, 32);
    if (valid && lane == 0) {
        float y = part + shb;
        if (bf16) ((__hip_bfloat16*)out)[node] = __float2bfloat16(y);
        else ((float*)out)[node] = y;
    }
}

extern "C" void kernel_launch(void* const* d_in, const int* in_sizes, int n_in,
                              void* d_out, int out_size, void* d_ws, size_t ws_size,
                              hipStream_t stream) {
    const void* x = d_in[0];
    const int* ei = (const int*)d_in[1];
    const void* w1l = d_in[2];
    const void* b1 = d_in[3];
    const void* w1r = d_in[4];
    const void* w2l = d_in[5];
    const void* b2 = d_in[6];
    const void* w2r = d_in[7];
    const void* head_w = d_in[8];
    const void* head_b = d_in[9];

    const int N = in_sizes[0] / MF;
    const int nE = in_sizes[1] / 2;
    const int nB = (N + 255) / 256;

    // workspace: flags(256B) | degi[N] | cur[N] | partials[1024] | srcs[nE]
    //            | xpack[N] | h[N*32] bf16   (~20.8 MB)
    int* flags = (int*)d_ws;
    int* degi = (int*)((char*)d_ws + 256);
    int* cur = degi + N;
    int* partials = cur + N;
    int* srcs = partials + 1024;
    unsigned int* xpack = (unsigned int*)(srcs + nE);
    __hip_bfloat16* h = (__hip_bfloat16*)(xpack + N);

    const size_t need = 256 + ((size_t)3 * N + 1024 + nE) * 4 + (size_t)N * HIDF * 2;
    if (ws_size < need || nB > 1024) return;  // visible failure (zero output)

    hipMemsetAsync(degi, 0, (size_t)N * 4, stream);

    const int eb4 = (nE + 1023) / 1024;  // 4 edges per thread
    const int gb = (N + NPB - 1) / NPB;
    k_detect<<<1, 64, 0, stream>>>((const unsigned int*)x, (const unsigned int*)ei, flags);
    k_pack<<<nB, 256, 0, stream>>>(x, flags, xpack, N);
    k_deg<<<eb4, 256, 0, stream>>>(ei, flags, degi, nE, N);
    k_scan1<<<nB, 256, 0, stream>>>(degi, partials, N);
    k_scan2<<<1, 1024, 0, stream>>>(partials, nB);
    k_scan3<<<nB, 256, 0, stream>>>(degi, partials, cur, N);
    k_fill<<<eb4, 256, 0, stream>>>(ei, flags, cur, srcs, nE, N);
    k_layer1<<<gb, 256, 0, stream>>>(xpack, degi, cur, srcs, h, d_out, flags,
                                     w1l, b1, w1r, N);
    k_layer2<<<gb, 256, 0, stream>>>(degi, cur, srcs, h, d_out, flags,
                                     w2l, b2, w2r, head_w, head_b, N);
}

// Round 5
// 346.778 us; speedup vs baseline: 27.1508x; 1.6621x over previous
//
#include <hip/hip_runtime.h>
#include <hip/hip_bf16.h>

#define MF 24      // input feature dim
#define HIDF 32    // hidden dim
#define OUTF 16    // emb dim
#define ZDIM 88    // 3*MF + OUTF
#define NPB 8      // nodes per 256-thread block in gather kernels

#define NB 512     // dest-range buckets for CSR counting sort
#define EB 16384   // edges per partition block (64 per thread)
#define CAP 8192   // LDS staging capacity (edges) in k_csrC

union bf16x8 {
    float4 v;
    __hip_bfloat16 h[8];
};

// flagged scalar load: element i of a float array that is either bf16 or fp32
__device__ __forceinline__ float ldw(const void* p, size_t i, bool bf16) {
    return bf16 ? __bfloat162float(((const __hip_bfloat16*)p)[i])
                : ((const float*)p)[i];
}

// ---------------------------------------------------------------------------
// Detect input dtypes at runtime (deterministic, runs every launch).
// flags[0]=1 if float arrays are bf16-packed; flags[1]=1 if edge ints are i64.
// ---------------------------------------------------------------------------
__global__ __launch_bounds__(64) void k_detect(const unsigned int* __restrict__ xw,
                                               const unsigned int* __restrict__ ew,
                                               int* __restrict__ flags) {
    if (blockIdx.x == 0 && threadIdx.x == 0) {
        int bf = 0;
        for (int k = 0; k < 64; ++k)
            if ((xw[k] & 0xFFFFu) == 0x3F80u) bf = 1;
        int zc = 0;
        for (int k = 0; k < 64; ++k)
            if (ew[2 * k + 1] == 0u) zc++;
        flags[0] = bf;
        flags[1] = (zc >= 32) ? 1 : 0;
    }
}

// ---------------------------------------------------------------------------
// Pack binary x rows (24 wide) into u32 bitmasks. x values are exactly {0,1}.
// ---------------------------------------------------------------------------
__global__ __launch_bounds__(256) void k_pack(const void* __restrict__ x,
                                              const int* __restrict__ flags,
                                              unsigned int* __restrict__ xpack, int N) {
    const bool bf16 = flags[0] != 0;
    int n = blockIdx.x * 256 + threadIdx.x;
    if (n >= N) return;
    unsigned int m = 0;
    if (bf16) {
        const float4* xr = reinterpret_cast<const float4*>(
            (const __hip_bfloat16*)x + (size_t)n * MF);
        bf16x8 u;
#pragma unroll
        for (int q = 0; q < 3; ++q) {
            u.v = xr[q];
#pragma unroll
            for (int i = 0; i < 8; ++i)
                if (__bfloat162float(u.h[i]) != 0.f) m |= 1u << (q * 8 + i);
        }
    } else {
        const float* xr = (const float*)x + (size_t)n * MF;
#pragma unroll
        for (int k = 0; k < MF; ++k)
            if (xr[k] != 0.f) m |= 1u << k;
    }
    xpack[n] = m;
}

// ---------------------------------------------------------------------------
// CSR pass A: per-block LDS histogram over NB dest-range buckets.
// counts[blk][b] = #edges of block blk whose dest falls in bucket b.
// No global atomics.
// ---------------------------------------------------------------------------
__global__ __launch_bounds__(256) void k_histA(const int* __restrict__ ei,
                                               const int* __restrict__ flags,
                                               int* __restrict__ counts,
                                               int nE, int N, int W) {
    __shared__ int hist[NB];
    for (int i = threadIdx.x; i < NB; i += 256) hist[i] = 0;
    __syncthreads();
    const bool i64 = flags[1] != 0;
    size_t base = (size_t)blockIdx.x * EB;
    for (int i = threadIdx.x; i < EB; i += 256) {
        size_t e = base + i;
        if (e < (size_t)nE) {
            int c = i64 ? ei[2 * ((size_t)nE + e)] : ei[(size_t)nE + e];
            if ((unsigned)c < (unsigned)N) atomicAdd(&hist[c / W], 1);
        }
    }
    __syncthreads();
    for (int i = threadIdx.x; i < NB; i += 256)
        counts[(size_t)blockIdx.x * NB + i] = hist[i];
}

// ---------------------------------------------------------------------------
// CSR scan 1: per-bucket column scan over blocks. counts[blk][b] becomes the
// exclusive prefix (offset of block blk within bucket b); colSum[b] = total.
// One block per bucket. Requires nBlk <= 1024.
// ---------------------------------------------------------------------------
__global__ __launch_bounds__(1024) void k_colscan(int* __restrict__ counts,
                                                  int* __restrict__ colSum, int nBlk) {
    __shared__ int s[1024];
    int b = blockIdx.x, t = threadIdx.x;
    int v = (t < nBlk) ? counts[(size_t)t * NB + b] : 0;
    s[t] = v;
    __syncthreads();
    for (int off = 1; off < 1024; off <<= 1) {
        int y = (t >= off) ? s[t - off] : 0;
        __syncthreads();
        s[t] += y;
        __syncthreads();
    }
    if (t < nBlk) counts[(size_t)t * NB + b] = s[t] - v;
    if (t == 1023) colSum[b] = s[1023];
}

// ---------------------------------------------------------------------------
// CSR scan 2: exclusive scan of colSum -> bucketStart[0..NB].
// ---------------------------------------------------------------------------
__global__ __launch_bounds__(1024) void k_bstart(const int* __restrict__ colSum,
                                                 int* __restrict__ bucketStart) {
    __shared__ int s[1024];
    int t = threadIdx.x;
    int v = (t < NB) ? colSum[t] : 0;
    s[t] = v;
    __syncthreads();
    for (int off = 1; off < 1024; off <<= 1) {
        int y = (t >= off) ? s[t - off] : 0;
        __syncthreads();
        s[t] += y;
        __syncthreads();
    }
    if (t < NB) bucketStart[t] = s[t] - v;
    if (t == NB - 1) bucketStart[NB] = s[t];
}

// ---------------------------------------------------------------------------
// CSR pass B: deterministic scatter into bucket-major order. Only LDS atomics.
// part[pos] = src | (local_dest << 20). src < 2^17 (N<=131072), local < 256.
// ---------------------------------------------------------------------------
__global__ __launch_bounds__(256) void k_scatB(const int* __restrict__ ei,
                                               const int* __restrict__ flags,
                                               const int* __restrict__ counts,
                                               const int* __restrict__ bucketStart,
                                               unsigned int* __restrict__ part,
                                               int nE, int N, int W) {
    __shared__ int base[NB];
    __shared__ int cnt[NB];
    for (int i = threadIdx.x; i < NB; i += 256) {
        base[i] = bucketStart[i] + counts[(size_t)blockIdx.x * NB + i];
        cnt[i] = 0;
    }
    __syncthreads();
    const bool i64 = flags[1] != 0;
    size_t eb = (size_t)blockIdx.x * EB;
    for (int i = threadIdx.x; i < EB; i += 256) {
        size_t e = eb + i;
        if (e < (size_t)nE) {
            int r = i64 ? ei[2 * e] : ei[e];
            int c = i64 ? ei[2 * ((size_t)nE + e)] : ei[(size_t)nE + e];
            if ((unsigned)c < (unsigned)N) {
                int b = c / W;
                int ld = c - b * W;
                unsigned rr = ((unsigned)r < (unsigned)N) ? (unsigned)r : 0u;
                int pos = base[b] + atomicAdd(&cnt[b], 1);
                part[pos] = rr | ((unsigned)ld << 20);
            }
        }
    }
}

// ---------------------------------------------------------------------------
// CSR pass C: one block per bucket. LDS-staged in-place counting sort of the
// bucket region; writes degi[] and rowstart[] directly (no N-wide scan).
// ---------------------------------------------------------------------------
__global__ __launch_bounds__(256) void k_csrC(const int* __restrict__ bucketStart,
                                              unsigned int* __restrict__ part,
                                              int* __restrict__ degi,
                                              int* __restrict__ rowstart,
                                              int N, int W) {
    __shared__ unsigned int stage[CAP];
    __shared__ unsigned int sorted[CAP];
    __shared__ int hist[256];
    __shared__ int sc[256];
    __shared__ int cur[256];
    int b = blockIdx.x, t = threadIdx.x;
    int start = bucketStart[b];
    int bs = bucketStart[b + 1] - start;
    int node = b * W + t;

    hist[t] = 0;
    __syncthreads();

    if (bs > CAP) {  // statistically impossible for this graph; stay memory-safe
        if (t < W && node < N) { degi[node] = 0; rowstart[node] = start; }
        return;
    }

    for (int i = t; i < bs; i += 256) {
        unsigned int v = part[start + i];
        stage[i] = v;
        atomicAdd(&hist[v >> 20], 1);
    }
    __syncthreads();

    int v = hist[t];
    sc[t] = v;
    __syncthreads();
    for (int off = 1; off < 256; off <<= 1) {
        int y = (t >= off) ? sc[t - off] : 0;
        __syncthreads();
        sc[t] += y;
        __syncthreads();
    }
    int excl = sc[t] - v;
    if (t < W && node < N) {
        degi[node] = v;
        rowstart[node] = start + excl;
    }
    cur[t] = excl;
    __syncthreads();

    for (int i = t; i < bs; i += 256) {
        unsigned int v2 = stage[i];
        int pos = atomicAdd(&cur[v2 >> 20], 1);
        sorted[pos] = v2 & 0xFFFFFu;
    }
    __syncthreads();
    for (int i = t; i < bs; i += 256) part[start + i] = sorted[i];
}

// ---------------------------------------------------------------------------
// Layer 1 (bit-packed gather + node math): 32 lanes per node.
// ---------------------------------------------------------------------------
__global__ __launch_bounds__(256) void k_layer1(
    const unsigned int* __restrict__ xpack, const int* __restrict__ degi,
    const int* __restrict__ rowstart, const unsigned int* __restrict__ srcs,
    __hip_bfloat16* __restrict__ h, void* __restrict__ out,
    const int* __restrict__ flags,
    const void* __restrict__ w1l, const void* __restrict__ b1,
    const void* __restrict__ w1r, int N) {
    const bool bf16 = flags[0] != 0;
    __shared__ float swl[HIDF * 25];  // stride 25: conflict-free for lane*25+k
    __shared__ float swr[HIDF * 25];
    __shared__ float sb[HIDF];
    for (int i = threadIdx.x; i < HIDF * MF; i += 256) {
        int j = i / MF, k = i - j * MF;
        swl[j * 25 + k] = ldw(w1l, i, bf16);
        swr[j * 25 + k] = ldw(w1r, i, bf16);
    }
    if (threadIdx.x < HIDF) sb[threadIdx.x] = ldw(b1, threadIdx.x, bf16);
    __syncthreads();

    int lane = threadIdx.x & 31;
    int g = threadIdx.x >> 5;
    int node = blockIdx.x * NPB + g;
    if (node >= N) return;  // no barriers below

    int dg = degi[node];
    int p0 = rowstart[node];
    unsigned int xpn = xpack[node];

    int cnt = 0;
    int e = 0;
    for (; e + 4 <= dg; e += 4) {
        unsigned int a0 = xpack[srcs[p0 + e]];
        unsigned int a1 = xpack[srcs[p0 + e + 1]];
        unsigned int a2 = xpack[srcs[p0 + e + 2]];
        unsigned int a3 = xpack[srcs[p0 + e + 3]];
        cnt += ((a0 >> lane) & 1) + ((a1 >> lane) & 1) +
               ((a2 >> lane) & 1) + ((a3 >> lane) & 1);
    }
    for (; e < dg; ++e) cnt += (xpack[srcs[p0 + e]] >> lane) & 1;

    float inv = 1.f / fmaxf((float)dg, 1.f);
    float fv = (float)cnt * inv;          // lanes >= 24: cnt==0 -> fv==0
    float xv = (float)((xpn >> lane) & 1);

    if (lane < MF) {
        if (bf16) {
            __hip_bfloat16* z = (__hip_bfloat16*)out + N + (size_t)node * ZDIM;
            z[lane] = __float2bfloat16(xv);
            z[MF + lane] = __float2bfloat16(fv);
            z[2 * MF + lane] = __float2bfloat16(xv * fv);
        } else {
            float* z = (float*)out + N + (size_t)node * ZDIM;
            z[lane] = xv;
            z[MF + lane] = fv;
            z[2 * MF + lane] = xv * fv;
        }
    }

    float acc = sb[lane];
#pragma unroll
    for (int k = 0; k < MF; ++k) {
        float fk = __shfl(fv, k, 32);
        float xk = (float)((xpn >> k) & 1);
        acc += fk * swl[lane * 25 + k] + xk * swr[lane * 25 + k];
    }
    h[(size_t)node * HIDF + lane] = __float2bfloat16(fmaxf(acc, 0.f));
}

// ---------------------------------------------------------------------------
// Layer 2 (fused gather + node math + head): 32 lanes per node, unroll-4.
// ---------------------------------------------------------------------------
__global__ __launch_bounds__(256) void k_layer2(
    const int* __restrict__ degi, const int* __restrict__ rowstart,
    const unsigned int* __restrict__ srcs, const __hip_bfloat16* __restrict__ h,
    void* __restrict__ out, const int* __restrict__ flags,
    const void* __restrict__ w2l, const void* __restrict__ b2,
    const void* __restrict__ w2r, const void* __restrict__ head_w,
    const void* __restrict__ head_b, int N) {
    const bool bf16 = flags[0] != 0;
    __shared__ float swl[OUTF * 33];
    __shared__ float swr[OUTF * 33];
    __shared__ float sb2[OUTF];
    __shared__ float shw[ZDIM];
    __shared__ float shb;
    __shared__ float ags[NPB][HIDF];
    __shared__ float hvs[NPB][HIDF];
    __shared__ float embs[NPB][OUTF];
    for (int i = threadIdx.x; i < OUTF * HIDF; i += 256) {
        int o = i >> 5, j = i & 31;
        swl[o * 33 + j] = ldw(w2l, i, bf16);
        swr[o * 33 + j] = ldw(w2r, i, bf16);
    }
    if (threadIdx.x < OUTF) sb2[threadIdx.x] = ldw(b2, threadIdx.x, bf16);
    if (threadIdx.x < ZDIM) shw[threadIdx.x] = ldw(head_w, threadIdx.x, bf16);
    if (threadIdx.x == 0) shb = ldw(head_b, 0, bf16);
    __syncthreads();

    int lane = threadIdx.x & 31;
    int g = threadIdx.x >> 5;
    int node = blockIdx.x * NPB + g;
    bool valid = node < N;

    int dg = 0, p0 = 0;
    if (valid) {
        dg = degi[node];
        p0 = rowstart[node];
    }
    float sum = 0.f;
    if (valid) {
        float hv = __bfloat162float(h[(size_t)node * HIDF + lane]);
        int e = 0;
        for (; e + 4 <= dg; e += 4) {
            int s0 = srcs[p0 + e], s1 = srcs[p0 + e + 1];
            int s2 = srcs[p0 + e + 2], s3 = srcs[p0 + e + 3];
            float v0 = __bfloat162float(h[(size_t)s0 * HIDF + lane]);
            float v1 = __bfloat162float(h[(size_t)s1 * HIDF + lane]);
            float v2 = __bfloat162float(h[(size_t)s2 * HIDF + lane]);
            float v3 = __bfloat162float(h[(size_t)s3 * HIDF + lane]);
            sum += (v0 + v1) + (v2 + v3);
        }
        for (; e < dg; ++e) {
            int s = srcs[p0 + e];
            sum += __bfloat162float(h[(size_t)s * HIDF + lane]);
        }
        float inv = 1.f / fmaxf((float)dg, 1.f);
        ags[g][lane] = sum * inv;
        hvs[g][lane] = hv;
    }
    __syncthreads();
    if (valid && lane < OUTF) {
        float acc = sb2[lane];
#pragma unroll
        for (int j = 0; j < HIDF; ++j)
            acc += ags[g][j] * swl[lane * 33 + j] + hvs[g][j] * swr[lane * 33 + j];
        acc = fmaxf(acc, 0.f);
        embs[g][lane] = acc;
        if (bf16)
            ((__hip_bfloat16*)out + N + (size_t)node * ZDIM)[3 * MF + lane] =
                __float2bfloat16(acc);
        else
            ((float*)out + N + (size_t)node * ZDIM)[3 * MF + lane] = acc;
    }
    __syncthreads();

    float part = 0.f;
    if (valid) {
        size_t zb = (size_t)N + (size_t)node * ZDIM;
        float z0 = bf16 ? __bfloat162float(((const __hip_bfloat16*)out)[zb + lane])
                        : ((const float*)out)[zb + lane];
        part += z0 * shw[lane];
        float z1 = bf16 ? __bfloat162float(((const __hip_bfloat16*)out)[zb + lane + 32])
                        : ((const float*)out)[zb + lane + 32];
        part += z1 * shw[lane + 32];
        int f2 = lane + 64;
        if (f2 < 3 * MF) {
            float z2 = bf16 ? __bfloat162float(((const __hip_bfloat16*)out)[zb + f2])
                            : ((const float*)out)[zb + f2];
            part += z2 * shw[f2];
        } else if (f2 < ZDIM) {
            part += embs[g][f2 - 3 * MF] * shw[f2];
        }
    }
#pragma unroll
    for (int off = 16; off > 0; off >>= 1) part += __shfl_down(part, off, 32);
    if (valid && lane == 0) {
        float y = part + shb;
        if (bf16) ((__hip_bfloat16*)out)[node] = __float2bfloat16(y);
        else ((float*)out)[node] = y;
    }
}

extern "C" void kernel_launch(void* const* d_in, const int* in_sizes, int n_in,
                              void* d_out, int out_size, void* d_ws, size_t ws_size,
                              hipStream_t stream) {
    const void* x = d_in[0];
    const int* ei = (const int*)d_in[1];
    const void* w1l = d_in[2];
    const void* b1 = d_in[3];
    const void* w1r = d_in[4];
    const void* w2l = d_in[5];
    const void* b2 = d_in[6];
    const void* w2r = d_in[7];
    const void* head_w = d_in[8];
    const void* head_b = d_in[9];

    const int N = in_sizes[0] / MF;
    const int nE = in_sizes[1] / 2;
    const int W = (N + NB - 1) / NB;          // bucket width (dest ids per bucket)
    const int nBlkA = (nE + EB - 1) / EB;     // partition blocks

    // structural limits of the packing/scan (hold for N=100k, nE=3.2M)
    if (N > NB * 256 || N > 131072 || nBlkA > 1024) return;

    // workspace layout:
    // flags(256B) | bucketStart[NB+1] | colSum[NB] | degi[N] | rowstart[N]
    // | counts[nBlkA*NB] | part[nE] u32 (becomes final CSR srcs, in place)
    // | xpack[N] | h[N*32] bf16
    int* flags = (int*)d_ws;
    int* bucketStart = (int*)((char*)d_ws + 256);
    int* colSum = bucketStart + (NB + 1);
    int* degi = colSum + NB;
    int* rowstart = degi + N;
    int* counts = rowstart + N;
    unsigned int* part = (unsigned int*)(counts + (size_t)nBlkA * NB);
    unsigned int* xpack = part + nE;
    __hip_bfloat16* h = (__hip_bfloat16*)(xpack + N);

    const size_t need = 256 +
        ((size_t)(NB + 1) + NB + 2 * (size_t)N + (size_t)nBlkA * NB +
         (size_t)nE + (size_t)N) * 4 + (size_t)N * HIDF * 2;
    if (ws_size < need) return;  // visible failure (zero output)

    const int nB = (N + 255) / 256;
    const int gb = (N + NPB - 1) / NPB;
    k_detect<<<1, 64, 0, stream>>>((const unsigned int*)x, (const unsigned int*)ei, flags);
    k_pack<<<nB, 256, 0, stream>>>(x, flags, xpack, N);
    k_histA<<<nBlkA, 256, 0, stream>>>(ei, flags, counts, nE, N, W);
    k_colscan<<<NB, 1024, 0, stream>>>(counts, colSum, nBlkA);
    k_bstart<<<1, 1024, 0, stream>>>(colSum, bucketStart);
    k_scatB<<<nBlkA, 256, 0, stream>>>(ei, flags, counts, bucketStart, part, nE, N, W);
    k_csrC<<<NB, 256, 0, stream>>>(bucketStart, part, degi, rowstart, N, W);
    k_layer1<<<gb, 256, 0, stream>>>(xpack, degi, rowstart, part, h, d_out, flags,
                                     w1l, b1, w1r, N);
    k_layer2<<<gb, 256, 0, stream>>>(degi, rowstart, part, h, d_out, flags,
                                     w2l, b2, w2r, head_w, head_b, N);
}

// Round 6
// 310.222 us; speedup vs baseline: 30.3502x; 1.1178x over previous
//
#include <hip/hip_runtime.h>
#include <hip/hip_bf16.h>

#define MF 24      // input feature dim
#define HIDF 32    // hidden dim
#define OUTF 16    // emb dim
#define ZDIM 88    // 3*MF + OUTF
#define NPB 8      // nodes per 256-thread block in k_layer1
#define NPB2 16    // nodes per 256-thread block in k_layer2

#define NB 512     // dest-range buckets for CSR counting sort
#define EB 16384   // edges per partition block (64 per thread)
#define CAP 8192   // LDS staging capacity (edges) in k_csrC

union bf16x8 {
    float4 v;
    __hip_bfloat16 h[8];
};

// flagged scalar load: element i of a float array that is either bf16 or fp32
__device__ __forceinline__ float ldw(const void* p, size_t i, bool bf16) {
    return bf16 ? __bfloat162float(((const __hip_bfloat16*)p)[i])
                : ((const float*)p)[i];
}

// ---------------------------------------------------------------------------
// Detect input dtypes at runtime (deterministic, runs every launch).
// flags[0]=1 if float arrays are bf16-packed; flags[1]=1 if edge ints are i64.
// ---------------------------------------------------------------------------
__global__ __launch_bounds__(64) void k_detect(const unsigned int* __restrict__ xw,
                                               const unsigned int* __restrict__ ew,
                                               int* __restrict__ flags) {
    if (blockIdx.x == 0 && threadIdx.x == 0) {
        int bf = 0;
        for (int k = 0; k < 64; ++k)
            if ((xw[k] & 0xFFFFu) == 0x3F80u) bf = 1;
        int zc = 0;
        for (int k = 0; k < 64; ++k)
            if (ew[2 * k + 1] == 0u) zc++;
        flags[0] = bf;
        flags[1] = (zc >= 32) ? 1 : 0;
    }
}

// ---------------------------------------------------------------------------
// Pack binary x rows (24 wide) into u32 bitmasks. x values are exactly {0,1}.
// ---------------------------------------------------------------------------
__global__ __launch_bounds__(256) void k_pack(const void* __restrict__ x,
                                              const int* __restrict__ flags,
                                              unsigned int* __restrict__ xpack, int N) {
    const bool bf16 = flags[0] != 0;
    int n = blockIdx.x * 256 + threadIdx.x;
    if (n >= N) return;
    unsigned int m = 0;
    if (bf16) {
        const float4* xr = reinterpret_cast<const float4*>(
            (const __hip_bfloat16*)x + (size_t)n * MF);
        bf16x8 u;
#pragma unroll
        for (int q = 0; q < 3; ++q) {
            u.v = xr[q];
#pragma unroll
            for (int i = 0; i < 8; ++i)
                if (__bfloat162float(u.h[i]) != 0.f) m |= 1u << (q * 8 + i);
        }
    } else {
        const float* xr = (const float*)x + (size_t)n * MF;
#pragma unroll
        for (int k = 0; k < MF; ++k)
            if (xr[k] != 0.f) m |= 1u << k;
    }
    xpack[n] = m;
}

// ---------------------------------------------------------------------------
// CSR pass A: per-block LDS histogram over NB dest-range buckets.
// ---------------------------------------------------------------------------
__global__ __launch_bounds__(256) void k_histA(const int* __restrict__ ei,
                                               const int* __restrict__ flags,
                                               int* __restrict__ counts,
                                               int nE, int N, int W) {
    __shared__ int hist[NB];
    for (int i = threadIdx.x; i < NB; i += 256) hist[i] = 0;
    __syncthreads();
    const bool i64 = flags[1] != 0;
    size_t base = (size_t)blockIdx.x * EB;
    for (int i = threadIdx.x; i < EB; i += 256) {
        size_t e = base + i;
        if (e < (size_t)nE) {
            int c = i64 ? ei[2 * ((size_t)nE + e)] : ei[(size_t)nE + e];
            if ((unsigned)c < (unsigned)N) atomicAdd(&hist[c / W], 1);
        }
    }
    __syncthreads();
    for (int i = threadIdx.x; i < NB; i += 256)
        counts[(size_t)blockIdx.x * NB + i] = hist[i];
}

// ---------------------------------------------------------------------------
// CSR scan 1: per-bucket column scan over blocks (one block per bucket).
// ---------------------------------------------------------------------------
__global__ __launch_bounds__(1024) void k_colscan(int* __restrict__ counts,
                                                  int* __restrict__ colSum, int nBlk) {
    __shared__ int s[1024];
    int b = blockIdx.x, t = threadIdx.x;
    int v = (t < nBlk) ? counts[(size_t)t * NB + b] : 0;
    s[t] = v;
    __syncthreads();
    for (int off = 1; off < 1024; off <<= 1) {
        int y = (t >= off) ? s[t - off] : 0;
        __syncthreads();
        s[t] += y;
        __syncthreads();
    }
    if (t < nBlk) counts[(size_t)t * NB + b] = s[t] - v;
    if (t == 1023) colSum[b] = s[1023];
}

// ---------------------------------------------------------------------------
// CSR scan 2: exclusive scan of colSum -> bucketStart[0..NB].
// ---------------------------------------------------------------------------
__global__ __launch_bounds__(1024) void k_bstart(const int* __restrict__ colSum,
                                                 int* __restrict__ bucketStart) {
    __shared__ int s[1024];
    int t = threadIdx.x;
    int v = (t < NB) ? colSum[t] : 0;
    s[t] = v;
    __syncthreads();
    for (int off = 1; off < 1024; off <<= 1) {
        int y = (t >= off) ? s[t - off] : 0;
        __syncthreads();
        s[t] += y;
        __syncthreads();
    }
    if (t < NB) bucketStart[t] = s[t] - v;
    if (t == NB - 1) bucketStart[NB] = s[t];
}

// ---------------------------------------------------------------------------
// CSR pass B: deterministic scatter into bucket-major order. Only LDS atomics.
// part[pos] = src | (local_dest << 20). src < 2^17 (N<=131072), local < 256.
// ---------------------------------------------------------------------------
__global__ __launch_bounds__(256) void k_scatB(const int* __restrict__ ei,
                                               const int* __restrict__ flags,
                                               const int* __restrict__ counts,
                                               const int* __restrict__ bucketStart,
                                               unsigned int* __restrict__ part,
                                               int nE, int N, int W) {
    __shared__ int base[NB];
    __shared__ int cnt[NB];
    for (int i = threadIdx.x; i < NB; i += 256) {
        base[i] = bucketStart[i] + counts[(size_t)blockIdx.x * NB + i];
        cnt[i] = 0;
    }
    __syncthreads();
    const bool i64 = flags[1] != 0;
    size_t eb = (size_t)blockIdx.x * EB;
    for (int i = threadIdx.x; i < EB; i += 256) {
        size_t e = eb + i;
        if (e < (size_t)nE) {
            int r = i64 ? ei[2 * e] : ei[e];
            int c = i64 ? ei[2 * ((size_t)nE + e)] : ei[(size_t)nE + e];
            if ((unsigned)c < (unsigned)N) {
                int b = c / W;
                int ld = c - b * W;
                unsigned rr = ((unsigned)r < (unsigned)N) ? (unsigned)r : 0u;
                int pos = base[b] + atomicAdd(&cnt[b], 1);
                part[pos] = rr | ((unsigned)ld << 20);
            }
        }
    }
}

// ---------------------------------------------------------------------------
// CSR pass C: one block per bucket; LDS counting sort; writes degi/rowstart.
// ---------------------------------------------------------------------------
__global__ __launch_bounds__(256) void k_csrC(const int* __restrict__ bucketStart,
                                              unsigned int* __restrict__ part,
                                              int* __restrict__ degi,
                                              int* __restrict__ rowstart,
                                              int N, int W) {
    __shared__ unsigned int stage[CAP];
    __shared__ unsigned int sorted[CAP];
    __shared__ int hist[256];
    __shared__ int sc[256];
    __shared__ int cur[256];
    int b = blockIdx.x, t = threadIdx.x;
    int start = bucketStart[b];
    int bs = bucketStart[b + 1] - start;
    int node = b * W + t;

    hist[t] = 0;
    __syncthreads();

    if (bs > CAP) {  // statistically impossible for this graph; stay memory-safe
        if (t < W && node < N) { degi[node] = 0; rowstart[node] = start; }
        return;
    }

    for (int i = t; i < bs; i += 256) {
        unsigned int v = part[start + i];
        stage[i] = v;
        atomicAdd(&hist[v >> 20], 1);
    }
    __syncthreads();

    int v = hist[t];
    sc[t] = v;
    __syncthreads();
    for (int off = 1; off < 256; off <<= 1) {
        int y = (t >= off) ? sc[t - off] : 0;
        __syncthreads();
        sc[t] += y;
        __syncthreads();
    }
    int excl = sc[t] - v;
    if (t < W && node < N) {
        degi[node] = v;
        rowstart[node] = start + excl;
    }
    cur[t] = excl;
    __syncthreads();

    for (int i = t; i < bs; i += 256) {
        unsigned int v2 = stage[i];
        int pos = atomicAdd(&cur[v2 >> 20], 1);
        sorted[pos] = v2 & 0xFFFFFu;
    }
    __syncthreads();
    for (int i = t; i < bs; i += 256) part[start + i] = sorted[i];
}

// ---------------------------------------------------------------------------
// Layer 1 + projection: 32 lanes per node.
// frac1 via bit-count gather; z[0:72); h in registers/LDS (fp32);
// hl = h@W2l^T (bf16), st = b2 + h@W2r^T (bf16), ypart = sum_{f<72} z_f w_f.
// ---------------------------------------------------------------------------
__global__ __launch_bounds__(256) void k_layer1(
    const unsigned int* __restrict__ xpack, const int* __restrict__ degi,
    const int* __restrict__ rowstart, const unsigned int* __restrict__ srcs,
    void* __restrict__ out, const int* __restrict__ flags,
    const void* __restrict__ w1l, const void* __restrict__ b1,
    const void* __restrict__ w1r, const void* __restrict__ w2l,
    const void* __restrict__ b2, const void* __restrict__ w2r,
    const void* __restrict__ head_w,
    __hip_bfloat16* __restrict__ hl, __hip_bfloat16* __restrict__ st,
    float* __restrict__ ypart, int N) {
    const bool bf16 = flags[0] != 0;
    __shared__ float swl[HIDF * 25];  // stride 25: conflict-free for lane*25+k
    __shared__ float swr[HIDF * 25];
    __shared__ float sb[HIDF];
    __shared__ float s2l[OUTF * 33];
    __shared__ float s2r[OUTF * 33];
    __shared__ float sb2[OUTF];
    __shared__ float shw[3 * MF];
    __shared__ float hs[NPB][HIDF];
    for (int i = threadIdx.x; i < HIDF * MF; i += 256) {
        int j = i / MF, k = i - j * MF;
        swl[j * 25 + k] = ldw(w1l, i, bf16);
        swr[j * 25 + k] = ldw(w1r, i, bf16);
    }
    for (int i = threadIdx.x; i < OUTF * HIDF; i += 256) {
        int o = i >> 5, j = i & 31;
        s2l[o * 33 + j] = ldw(w2l, i, bf16);
        s2r[o * 33 + j] = ldw(w2r, i, bf16);
    }
    if (threadIdx.x < HIDF) sb[threadIdx.x] = ldw(b1, threadIdx.x, bf16);
    if (threadIdx.x < OUTF) sb2[threadIdx.x] = ldw(b2, threadIdx.x, bf16);
    if (threadIdx.x < 3 * MF) shw[threadIdx.x] = ldw(head_w, threadIdx.x, bf16);
    __syncthreads();

    int lane = threadIdx.x & 31;
    int g = threadIdx.x >> 5;
    int node = blockIdx.x * NPB + g;
    bool valid = node < N;

    int dg = 0, p0 = 0;
    unsigned int xpn = 0;
    if (valid) {
        dg = degi[node];
        p0 = rowstart[node];
        xpn = xpack[node];
    }

    int cnt = 0;
    int e = 0;
    for (; e + 4 <= dg; e += 4) {
        unsigned int a0 = xpack[srcs[p0 + e]];
        unsigned int a1 = xpack[srcs[p0 + e + 1]];
        unsigned int a2 = xpack[srcs[p0 + e + 2]];
        unsigned int a3 = xpack[srcs[p0 + e + 3]];
        cnt += ((a0 >> lane) & 1) + ((a1 >> lane) & 1) +
               ((a2 >> lane) & 1) + ((a3 >> lane) & 1);
    }
    for (; e < dg; ++e) cnt += (xpack[srcs[p0 + e]] >> lane) & 1;

    float inv = 1.f / fmaxf((float)dg, 1.f);
    float fv = (float)cnt * inv;          // lanes >= 24: cnt==0 -> fv==0
    float xv = (float)((xpn >> lane) & 1);

    float pc = 0.f;
    if (valid && lane < MF) {
        if (bf16) {
            __hip_bfloat16* z = (__hip_bfloat16*)out + N + (size_t)node * ZDIM;
            z[lane] = __float2bfloat16(xv);
            z[MF + lane] = __float2bfloat16(fv);
            z[2 * MF + lane] = __float2bfloat16(xv * fv);
        } else {
            float* z = (float*)out + N + (size_t)node * ZDIM;
            z[lane] = xv;
            z[MF + lane] = fv;
            z[2 * MF + lane] = xv * fv;
        }
        pc = xv * shw[lane] + fv * shw[MF + lane] + xv * fv * shw[2 * MF + lane];
    }

    // h_j for lane j (fp32, relu'd)
    float acc = sb[lane];
#pragma unroll
    for (int k = 0; k < MF; ++k) {
        float fk = __shfl(fv, k, 32);
        float xk = (float)((xpn >> k) & 1);
        acc += fk * swl[lane * 25 + k] + xk * swr[lane * 25 + k];
    }
    hs[g][lane] = fmaxf(acc, 0.f);

    // reduce head partial across the 32-lane group
#pragma unroll
    for (int off = 16; off > 0; off >>= 1) pc += __shfl_down(pc, off, 32);
    __syncthreads();

    // project: half 0 -> hl[o] = h . W2l[o], half 1 -> st[o] = b2[o] + h . W2r[o]
    int o = lane & 15;
    int half = lane >> 4;
    const float* wrow = (half ? s2r : s2l) + o * 33;
    float d = 0.f;
#pragma unroll
    for (int j = 0; j < HIDF; ++j) d += hs[g][j] * wrow[j];
    if (valid) {
        if (half == 0) hl[(size_t)node * OUTF + o] = __float2bfloat16(d);
        else st[(size_t)node * OUTF + o] = __float2bfloat16(d + sb2[o]);
        if (lane == 0) ypart[node] = pc;
    }
}

// ---------------------------------------------------------------------------
// Layer 2 (projected gather + head): 16 lanes per node.
// emb = relu(mean(hl[src]) + st); z[72:88); yhat = ypart + emb.w_head + b.
// ---------------------------------------------------------------------------
__global__ __launch_bounds__(256) void k_layer2(
    const int* __restrict__ degi, const int* __restrict__ rowstart,
    const unsigned int* __restrict__ srcs, const __hip_bfloat16* __restrict__ hl,
    const __hip_bfloat16* __restrict__ st, const float* __restrict__ ypart,
    void* __restrict__ out, const int* __restrict__ flags,
    const void* __restrict__ head_w, const void* __restrict__ head_b, int N) {
    const bool bf16 = flags[0] != 0;
    __shared__ float shw2[OUTF];
    __shared__ float shb;
    if (threadIdx.x < OUTF) shw2[threadIdx.x] = ldw(head_w, 3 * MF + threadIdx.x, bf16);
    if (threadIdx.x == 0) shb = ldw(head_b, 0, bf16);
    __syncthreads();

    int lane = threadIdx.x & 15;
    int g = threadIdx.x >> 4;
    int node = blockIdx.x * NPB2 + g;
    bool valid = node < N;

    int dg = 0, p0 = 0;
    if (valid) {
        dg = degi[node];
        p0 = rowstart[node];
    }
    float sum = 0.f;
    int e = 0;
    for (; e + 4 <= dg; e += 4) {
        int s0 = srcs[p0 + e], s1 = srcs[p0 + e + 1];
        int s2 = srcs[p0 + e + 2], s3 = srcs[p0 + e + 3];
        float v0 = __bfloat162float(hl[(size_t)s0 * OUTF + lane]);
        float v1 = __bfloat162float(hl[(size_t)s1 * OUTF + lane]);
        float v2 = __bfloat162float(hl[(size_t)s2 * OUTF + lane]);
        float v3 = __bfloat162float(hl[(size_t)s3 * OUTF + lane]);
        sum += (v0 + v1) + (v2 + v3);
    }
    for (; e < dg; ++e)
        sum += __bfloat162float(hl[(size_t)srcs[p0 + e] * OUTF + lane]);

    float emb = 0.f;
    if (valid) {
        float inv = 1.f / fmaxf((float)dg, 1.f);
        emb = fmaxf(sum * inv + __bfloat162float(st[(size_t)node * OUTF + lane]), 0.f);
        if (bf16)
            ((__hip_bfloat16*)out + N + (size_t)node * ZDIM)[3 * MF + lane] =
                __float2bfloat16(emb);
        else
            ((float*)out + N + (size_t)node * ZDIM)[3 * MF + lane] = emb;
    }
    float part = emb * shw2[lane];
#pragma unroll
    for (int off = 8; off > 0; off >>= 1) part += __shfl_down(part, off, 16);
    if (valid && lane == 0) {
        float y = ypart[node] + part + shb;
        if (bf16) ((__hip_bfloat16*)out)[node] = __float2bfloat16(y);
        else ((float*)out)[node] = y;
    }
}

extern "C" void kernel_launch(void* const* d_in, const int* in_sizes, int n_in,
                              void* d_out, int out_size, void* d_ws, size_t ws_size,
                              hipStream_t stream) {
    const void* x = d_in[0];
    const int* ei = (const int*)d_in[1];
    const void* w1l = d_in[2];
    const void* b1 = d_in[3];
    const void* w1r = d_in[4];
    const void* w2l = d_in[5];
    const void* b2 = d_in[6];
    const void* w2r = d_in[7];
    const void* head_w = d_in[8];
    const void* head_b = d_in[9];

    const int N = in_sizes[0] / MF;
    const int nE = in_sizes[1] / 2;
    const int W = (N + NB - 1) / NB;          // bucket width (dest ids per bucket)
    const int nBlkA = (nE + EB - 1) / EB;     // partition blocks

    // structural limits (hold for N=100k, nE=3.2M); ypart aliases counts
    if (N > NB * 256 || N > 131072 || nBlkA > 1024 ||
        (size_t)nBlkA * NB < (size_t)N) return;

    // workspace layout:
    // flags(256B) | bucketStart[NB+1] | colSum[NB] | degi[N] | rowstart[N]
    // | counts[nBlkA*NB] (reused as ypart[N] f32 after k_scatB)
    // | part[nE] u32 (becomes final CSR srcs, in place)
    // | xpack[N] | hl[N*16] bf16 | st[N*16] bf16
    int* flags = (int*)d_ws;
    int* bucketStart = (int*)((char*)d_ws + 256);
    int* colSum = bucketStart + (NB + 1);
    int* degi = colSum + NB;
    int* rowstart = degi + N;
    int* counts = rowstart + N;
    unsigned int* part = (unsigned int*)(counts + (size_t)nBlkA * NB);
    unsigned int* xpack = part + nE;
    __hip_bfloat16* hl = (__hip_bfloat16*)(xpack + N);
    __hip_bfloat16* st = hl + (size_t)N * OUTF;
    float* ypart = (float*)counts;  // counts is dead after k_scatB

    const size_t need = 256 +
        ((size_t)(NB + 1) + NB + 2 * (size_t)N + (size_t)nBlkA * NB +
         (size_t)nE + (size_t)N) * 4 + (size_t)N * OUTF * 2 * 2;
    if (ws_size < need) return;  // visible failure (zero output)

    const int nB = (N + 255) / 256;
    const int gb = (N + NPB - 1) / NPB;
    const int gb2 = (N + NPB2 - 1) / NPB2;
    k_detect<<<1, 64, 0, stream>>>((const unsigned int*)x, (const unsigned int*)ei, flags);
    k_pack<<<nB, 256, 0, stream>>>(x, flags, xpack, N);
    k_histA<<<nBlkA, 256, 0, stream>>>(ei, flags, counts, nE, N, W);
    k_colscan<<<NB, 1024, 0, stream>>>(counts, colSum, nBlkA);
    k_bstart<<<1, 1024, 0, stream>>>(colSum, bucketStart);
    k_scatB<<<nBlkA, 256, 0, stream>>>(ei, flags, counts, bucketStart, part, nE, N, W);
    k_csrC<<<NB, 256, 0, stream>>>(bucketStart, part, degi, rowstart, N, W);
    k_layer1<<<gb, 256, 0, stream>>>(xpack, degi, rowstart, part, d_out, flags,
                                     w1l, b1, w1r, w2l, b2, w2r, head_w,
                                     hl, st, ypart, N);
    k_layer2<<<gb2, 256, 0, stream>>>(degi, rowstart, part, hl, st, ypart,
                                      d_out, flags, head_w, head_b, N);
}

// Round 7
// 305.121 us; speedup vs baseline: 30.8577x; 1.0167x over previous
//
#include <hip/hip_runtime.h>
#include <hip/hip_bf16.h>

#define MF 24      // input feature dim
#define HIDF 32    // hidden dim
#define OUTF 16    // emb dim
#define ZDIM 88    // 3*MF + OUTF
#define NPB 8      // nodes per 256-thread block in k_layer1
#define NPB2 16    // nodes per 256-thread block in k_layer2

#define NB 512     // dest-range buckets for CSR counting sort
#define EB 16384   // edges per partition block (64 per thread)
#define CAP 8192   // LDS staging capacity (edges) in k_csrC

union bf16x8 {
    float4 v;
    __hip_bfloat16 h[8];
};

// flagged scalar load: element i of a float array that is either bf16 or fp32
__device__ __forceinline__ float ldw(const void* p, size_t i, bool bf16) {
    return bf16 ? __bfloat162float(((const __hip_bfloat16*)p)[i])
                : ((const float*)p)[i];
}

// ---------------------------------------------------------------------------
// Detect input dtypes at runtime (deterministic, runs every launch).
// flags[0]=1 if float arrays are bf16-packed; flags[1]=1 if edge ints are i64.
// ---------------------------------------------------------------------------
__global__ __launch_bounds__(64) void k_detect(const unsigned int* __restrict__ xw,
                                               const unsigned int* __restrict__ ew,
                                               int* __restrict__ flags) {
    if (blockIdx.x == 0 && threadIdx.x == 0) {
        int bf = 0;
        for (int k = 0; k < 64; ++k)
            if ((xw[k] & 0xFFFFu) == 0x3F80u) bf = 1;
        int zc = 0;
        for (int k = 0; k < 64; ++k)
            if (ew[2 * k + 1] == 0u) zc++;
        flags[0] = bf;
        flags[1] = (zc >= 32) ? 1 : 0;
    }
}

// ---------------------------------------------------------------------------
// Pack binary x rows (24 wide) into u32 bitmasks. x values are exactly {0,1}.
// ---------------------------------------------------------------------------
__global__ __launch_bounds__(256) void k_pack(const void* __restrict__ x,
                                              const int* __restrict__ flags,
                                              unsigned int* __restrict__ xpack, int N) {
    const bool bf16 = flags[0] != 0;
    int n = blockIdx.x * 256 + threadIdx.x;
    if (n >= N) return;
    unsigned int m = 0;
    if (bf16) {
        const float4* xr = reinterpret_cast<const float4*>(
            (const __hip_bfloat16*)x + (size_t)n * MF);
        bf16x8 u;
#pragma unroll
        for (int q = 0; q < 3; ++q) {
            u.v = xr[q];
#pragma unroll
            for (int i = 0; i < 8; ++i)
                if (__bfloat162float(u.h[i]) != 0.f) m |= 1u << (q * 8 + i);
        }
    } else {
        const float* xr = (const float*)x + (size_t)n * MF;
#pragma unroll
        for (int k = 0; k < MF; ++k)
            if (xr[k] != 0.f) m |= 1u << k;
    }
    xpack[n] = m;
}

// ---------------------------------------------------------------------------
// CSR pass A: per-block LDS histogram over NB dest-range buckets.
// ---------------------------------------------------------------------------
__global__ __launch_bounds__(256) void k_histA(const int* __restrict__ ei,
                                               const int* __restrict__ flags,
                                               int* __restrict__ counts,
                                               int nE, int N, int W) {
    __shared__ int hist[NB];
    for (int i = threadIdx.x; i < NB; i += 256) hist[i] = 0;
    __syncthreads();
    const bool i64 = flags[1] != 0;
    size_t base = (size_t)blockIdx.x * EB;
    for (int i = threadIdx.x; i < EB; i += 256) {
        size_t e = base + i;
        if (e < (size_t)nE) {
            int c = i64 ? ei[2 * ((size_t)nE + e)] : ei[(size_t)nE + e];
            if ((unsigned)c < (unsigned)N) atomicAdd(&hist[c / W], 1);
        }
    }
    __syncthreads();
    for (int i = threadIdx.x; i < NB; i += 256)
        counts[(size_t)blockIdx.x * NB + i] = hist[i];
}

// ---------------------------------------------------------------------------
// CSR scan 1: per-bucket column scan over blocks (one block per bucket).
// ---------------------------------------------------------------------------
__global__ __launch_bounds__(1024) void k_colscan(int* __restrict__ counts,
                                                  int* __restrict__ colSum, int nBlk) {
    __shared__ int s[1024];
    int b = blockIdx.x, t = threadIdx.x;
    int v = (t < nBlk) ? counts[(size_t)t * NB + b] : 0;
    s[t] = v;
    __syncthreads();
    for (int off = 1; off < 1024; off <<= 1) {
        int y = (t >= off) ? s[t - off] : 0;
        __syncthreads();
        s[t] += y;
        __syncthreads();
    }
    if (t < nBlk) counts[(size_t)t * NB + b] = s[t] - v;
    if (t == 1023) colSum[b] = s[1023];
}

// ---------------------------------------------------------------------------
// CSR scan 2: exclusive scan of colSum -> bucketStart[0..NB].
// ---------------------------------------------------------------------------
__global__ __launch_bounds__(1024) void k_bstart(const int* __restrict__ colSum,
                                                 int* __restrict__ bucketStart) {
    __shared__ int s[1024];
    int t = threadIdx.x;
    int v = (t < NB) ? colSum[t] : 0;
    s[t] = v;
    __syncthreads();
    for (int off = 1; off < 1024; off <<= 1) {
        int y = (t >= off) ? s[t - off] : 0;
        __syncthreads();
        s[t] += y;
        __syncthreads();
    }
    if (t < NB) bucketStart[t] = s[t] - v;
    if (t == NB - 1) bucketStart[NB] = s[t];
}

// ---------------------------------------------------------------------------
// CSR pass B: deterministic scatter into bucket-major order. Only LDS atomics.
// part[pos] = src | (local_dest << 20). src < 2^17 (N<=131072), local < 256.
// ---------------------------------------------------------------------------
__global__ __launch_bounds__(256) void k_scatB(const int* __restrict__ ei,
                                               const int* __restrict__ flags,
                                               const int* __restrict__ counts,
                                               const int* __restrict__ bucketStart,
                                               unsigned int* __restrict__ part,
                                               int nE, int N, int W) {
    __shared__ int base[NB];
    __shared__ int cnt[NB];
    for (int i = threadIdx.x; i < NB; i += 256) {
        base[i] = bucketStart[i] + counts[(size_t)blockIdx.x * NB + i];
        cnt[i] = 0;
    }
    __syncthreads();
    const bool i64 = flags[1] != 0;
    size_t eb = (size_t)blockIdx.x * EB;
    for (int i = threadIdx.x; i < EB; i += 256) {
        size_t e = eb + i;
        if (e < (size_t)nE) {
            int r = i64 ? ei[2 * e] : ei[e];
            int c = i64 ? ei[2 * ((size_t)nE + e)] : ei[(size_t)nE + e];
            if ((unsigned)c < (unsigned)N) {
                int b = c / W;
                int ld = c - b * W;
                unsigned rr = ((unsigned)r < (unsigned)N) ? (unsigned)r : 0u;
                int pos = base[b] + atomicAdd(&cnt[b], 1);
                part[pos] = rr | ((unsigned)ld << 20);
            }
        }
    }
}

// ---------------------------------------------------------------------------
// CSR pass C: one block per bucket; LDS counting sort; writes degi/rowstart.
// ---------------------------------------------------------------------------
__global__ __launch_bounds__(256) void k_csrC(const int* __restrict__ bucketStart,
                                              unsigned int* __restrict__ part,
                                              int* __restrict__ degi,
                                              int* __restrict__ rowstart,
                                              int N, int W) {
    __shared__ unsigned int stage[CAP];
    __shared__ unsigned int sorted[CAP];
    __shared__ int hist[256];
    __shared__ int sc[256];
    __shared__ int cur[256];
    int b = blockIdx.x, t = threadIdx.x;
    int start = bucketStart[b];
    int bs = bucketStart[b + 1] - start;
    int node = b * W + t;

    hist[t] = 0;
    __syncthreads();

    if (bs > CAP) {  // statistically impossible for this graph; stay memory-safe
        if (t < W && node < N) { degi[node] = 0; rowstart[node] = start; }
        return;
    }

    for (int i = t; i < bs; i += 256) {
        unsigned int v = part[start + i];
        stage[i] = v;
        atomicAdd(&hist[v >> 20], 1);
    }
    __syncthreads();

    int v = hist[t];
    sc[t] = v;
    __syncthreads();
    for (int off = 1; off < 256; off <<= 1) {
        int y = (t >= off) ? sc[t - off] : 0;
        __syncthreads();
        sc[t] += y;
        __syncthreads();
    }
    int excl = sc[t] - v;
    if (t < W && node < N) {
        degi[node] = v;
        rowstart[node] = start + excl;
    }
    cur[t] = excl;
    __syncthreads();

    for (int i = t; i < bs; i += 256) {
        unsigned int v2 = stage[i];
        int pos = atomicAdd(&cur[v2 >> 20], 1);
        sorted[pos] = v2 & 0xFFFFFu;
    }
    __syncthreads();
    for (int i = t; i < bs; i += 256) part[start + i] = sorted[i];
}

// ---------------------------------------------------------------------------
// Layer 1 + projection: 32 lanes per node, EDGE-PARALLEL bit-count gather.
// Lane i loads edge p0+i (coalesced srcs read, 32 xpack loads in flight);
// 24 wave-wide ballots turn per-edge masks into per-bit counts (lane b keeps
// popcount of its group's 32-bit ballot half). Then z[0:72), h, projections.
// ---------------------------------------------------------------------------
__global__ __launch_bounds__(256) void k_layer1(
    const unsigned int* __restrict__ xpack, const int* __restrict__ degi,
    const int* __restrict__ rowstart, const unsigned int* __restrict__ srcs,
    void* __restrict__ out, const int* __restrict__ flags,
    const void* __restrict__ w1l, const void* __restrict__ b1,
    const void* __restrict__ w1r, const void* __restrict__ w2l,
    const void* __restrict__ b2, const void* __restrict__ w2r,
    const void* __restrict__ head_w,
    __hip_bfloat16* __restrict__ hl, __hip_bfloat16* __restrict__ st,
    float* __restrict__ ypart, int N) {
    const bool bf16 = flags[0] != 0;
    __shared__ float swl[HIDF * 25];  // stride 25: conflict-free for lane*25+k
    __shared__ float swr[HIDF * 25];
    __shared__ float sb[HIDF];
    __shared__ float s2l[OUTF * 33];
    __shared__ float s2r[OUTF * 33];
    __shared__ float sb2[OUTF];
    __shared__ float shw[3 * MF];
    __shared__ float hs[NPB][HIDF];
    for (int i = threadIdx.x; i < HIDF * MF; i += 256) {
        int j = i / MF, k = i - j * MF;
        swl[j * 25 + k] = ldw(w1l, i, bf16);
        swr[j * 25 + k] = ldw(w1r, i, bf16);
    }
    for (int i = threadIdx.x; i < OUTF * HIDF; i += 256) {
        int o = i >> 5, j = i & 31;
        s2l[o * 33 + j] = ldw(w2l, i, bf16);
        s2r[o * 33 + j] = ldw(w2r, i, bf16);
    }
    if (threadIdx.x < HIDF) sb[threadIdx.x] = ldw(b1, threadIdx.x, bf16);
    if (threadIdx.x < OUTF) sb2[threadIdx.x] = ldw(b2, threadIdx.x, bf16);
    if (threadIdx.x < 3 * MF) shw[threadIdx.x] = ldw(head_w, threadIdx.x, bf16);
    __syncthreads();

    int lane = threadIdx.x & 31;
    int g = threadIdx.x >> 5;
    int halfShift = threadIdx.x & 32;  // which 32-bit half of the wave ballot
    int node = blockIdx.x * NPB + g;
    bool valid = node < N;

    int dg = 0, p0 = 0;
    unsigned int xpn = 0;
    if (valid) {
        dg = degi[node];
        p0 = rowstart[node];
        xpn = xpack[node];
    }

    // edge-parallel gather: lane i handles edges p0+i, p0+32+i, ...
    int cnt = 0;
    for (int base = 0; base < dg; base += 32) {
        int e = base + lane;
        unsigned int m = 0;
        if (e < dg) m = xpack[srcs[p0 + e]];
#pragma unroll
        for (int b = 0; b < MF; ++b) {
            unsigned long long bal = __ballot(((m >> b) & 1u) != 0u);
            unsigned int halfb = (unsigned int)(bal >> halfShift);
            cnt += (lane == b) ? __popc(halfb) : 0;
        }
    }

    float inv = 1.f / fmaxf((float)dg, 1.f);
    float fv = (float)cnt * inv;          // lanes >= 24: cnt==0 -> fv==0
    float xv = (float)((xpn >> lane) & 1);

    float pc = 0.f;
    if (valid && lane < MF) {
        if (bf16) {
            __hip_bfloat16* z = (__hip_bfloat16*)out + N + (size_t)node * ZDIM;
            z[lane] = __float2bfloat16(xv);
            z[MF + lane] = __float2bfloat16(fv);
            z[2 * MF + lane] = __float2bfloat16(xv * fv);
        } else {
            float* z = (float*)out + N + (size_t)node * ZDIM;
            z[lane] = xv;
            z[MF + lane] = fv;
            z[2 * MF + lane] = xv * fv;
        }
        pc = xv * shw[lane] + fv * shw[MF + lane] + xv * fv * shw[2 * MF + lane];
    }

    // h_j for lane j (fp32, relu'd) — hs[g] written & read by the same
    // half-wave; in-wave LDS ordering makes a barrier unnecessary.
    float acc = sb[lane];
#pragma unroll
    for (int k = 0; k < MF; ++k) {
        float fk = __shfl(fv, k, 32);
        float xk = (float)((xpn >> k) & 1);
        acc += fk * swl[lane * 25 + k] + xk * swr[lane * 25 + k];
    }
    hs[g][lane] = fmaxf(acc, 0.f);

    // reduce head partial across the 32-lane group
#pragma unroll
    for (int off = 16; off > 0; off >>= 1) pc += __shfl_down(pc, off, 32);

    // project: half 0 -> hl[o] = h . W2l[o], half 1 -> st[o] = b2[o] + h . W2r[o]
    int o = lane & 15;
    int half = lane >> 4;
    const float* wrow = (half ? s2r : s2l) + o * 33;
    float d = 0.f;
#pragma unroll
    for (int j = 0; j < HIDF; ++j) d += hs[g][j] * wrow[j];
    if (valid) {
        if (half == 0) hl[(size_t)node * OUTF + o] = __float2bfloat16(d);
        else st[(size_t)node * OUTF + o] = __float2bfloat16(d + sb2[o]);
        if (lane == 0) ypart[node] = pc;
    }
}

// ---------------------------------------------------------------------------
// Layer 2 (projected gather + head): 16 lanes per node.
// emb = relu(mean(hl[src]) + st); z[72:88); yhat = ypart + emb.w_head + b.
// ---------------------------------------------------------------------------
__global__ __launch_bounds__(256) void k_layer2(
    const int* __restrict__ degi, const int* __restrict__ rowstart,
    const unsigned int* __restrict__ srcs, const __hip_bfloat16* __restrict__ hl,
    const __hip_bfloat16* __restrict__ st, const float* __restrict__ ypart,
    void* __restrict__ out, const int* __restrict__ flags,
    const void* __restrict__ head_w, const void* __restrict__ head_b, int N) {
    const bool bf16 = flags[0] != 0;
    __shared__ float shw2[OUTF];
    __shared__ float shb;
    if (threadIdx.x < OUTF) shw2[threadIdx.x] = ldw(head_w, 3 * MF + threadIdx.x, bf16);
    if (threadIdx.x == 0) shb = ldw(head_b, 0, bf16);
    __syncthreads();

    int lane = threadIdx.x & 15;
    int g = threadIdx.x >> 4;
    int node = blockIdx.x * NPB2 + g;
    bool valid = node < N;

    int dg = 0, p0 = 0;
    if (valid) {
        dg = degi[node];
        p0 = rowstart[node];
    }
    float sum = 0.f;
    int e = 0;
    for (; e + 4 <= dg; e += 4) {
        int s0 = srcs[p0 + e], s1 = srcs[p0 + e + 1];
        int s2 = srcs[p0 + e + 2], s3 = srcs[p0 + e + 3];
        float v0 = __bfloat162float(hl[(size_t)s0 * OUTF + lane]);
        float v1 = __bfloat162float(hl[(size_t)s1 * OUTF + lane]);
        float v2 = __bfloat162float(hl[(size_t)s2 * OUTF + lane]);
        float v3 = __bfloat162float(hl[(size_t)s3 * OUTF + lane]);
        sum += (v0 + v1) + (v2 + v3);
    }
    for (; e < dg; ++e)
        sum += __bfloat162float(hl[(size_t)srcs[p0 + e] * OUTF + lane]);

    float emb = 0.f;
    if (valid) {
        float inv = 1.f / fmaxf((float)dg, 1.f);
        emb = fmaxf(sum * inv + __bfloat162float(st[(size_t)node * OUTF + lane]), 0.f);
        if (bf16)
            ((__hip_bfloat16*)out + N + (size_t)node * ZDIM)[3 * MF + lane] =
                __float2bfloat16(emb);
        else
            ((float*)out + N + (size_t)node * ZDIM)[3 * MF + lane] = emb;
    }
    float part = emb * shw2[lane];
#pragma unroll
    for (int off = 8; off > 0; off >>= 1) part += __shfl_down(part, off, 16);
    if (valid && lane == 0) {
        float y = ypart[node] + part + shb;
        if (bf16) ((__hip_bfloat16*)out)[node] = __float2bfloat16(y);
        else ((float*)out)[node] = y;
    }
}

extern "C" void kernel_launch(void* const* d_in, const int* in_sizes, int n_in,
                              void* d_out, int out_size, void* d_ws, size_t ws_size,
                              hipStream_t stream) {
    const void* x = d_in[0];
    const int* ei = (const int*)d_in[1];
    const void* w1l = d_in[2];
    const void* b1 = d_in[3];
    const void* w1r = d_in[4];
    const void* w2l = d_in[5];
    const void* b2 = d_in[6];
    const void* w2r = d_in[7];
    const void* head_w = d_in[8];
    const void* head_b = d_in[9];

    const int N = in_sizes[0] / MF;
    const int nE = in_sizes[1] / 2;
    const int W = (N + NB - 1) / NB;          // bucket width (dest ids per bucket)
    const int nBlkA = (nE + EB - 1) / EB;     // partition blocks

    // structural limits (hold for N=100k, nE=3.2M); ypart aliases counts
    if (N > NB * 256 || N > 131072 || nBlkA > 1024 ||
        (size_t)nBlkA * NB < (size_t)N) return;

    // workspace layout:
    // flags(256B) | bucketStart[NB+1] | colSum[NB] | degi[N] | rowstart[N]
    // | counts[nBlkA*NB] (reused as ypart[N] f32 after k_scatB)
    // | part[nE] u32 (becomes final CSR srcs, in place)
    // | xpack[N] | hl[N*16] bf16 | st[N*16] bf16
    int* flags = (int*)d_ws;
    int* bucketStart = (int*)((char*)d_ws + 256);
    int* colSum = bucketStart + (NB + 1);
    int* degi = colSum + NB;
    int* rowstart = degi + N;
    int* counts = rowstart + N;
    unsigned int* part = (unsigned int*)(counts + (size_t)nBlkA * NB);
    unsigned int* xpack = part + nE;
    __hip_bfloat16* hl = (__hip_bfloat16*)(xpack + N);
    __hip_bfloat16* st = hl + (size_t)N * OUTF;
    float* ypart = (float*)counts;  // counts is dead after k_scatB

    const size_t need = 256 +
        ((size_t)(NB + 1) + NB + 2 * (size_t)N + (size_t)nBlkA * NB +
         (size_t)nE + (size_t)N) * 4 + (size_t)N * OUTF * 2 * 2;
    if (ws_size < need) return;  // visible failure (zero output)

    const int nB = (N + 255) / 256;
    const int gb = (N + NPB - 1) / NPB;
    const int gb2 = (N + NPB2 - 1) / NPB2;
    k_detect<<<1, 64, 0, stream>>>((const unsigned int*)x, (const unsigned int*)ei, flags);
    k_pack<<<nB, 256, 0, stream>>>(x, flags, xpack, N);
    k_histA<<<nBlkA, 256, 0, stream>>>(ei, flags, counts, nE, N, W);
    k_colscan<<<NB, 1024, 0, stream>>>(counts, colSum, nBlkA);
    k_bstart<<<1, 1024, 0, stream>>>(colSum, bucketStart);
    k_scatB<<<nBlkA, 256, 0, stream>>>(ei, flags, counts, bucketStart, part, nE, N, W);
    k_csrC<<<NB, 256, 0, stream>>>(bucketStart, part, degi, rowstart, N, W);
    k_layer1<<<gb, 256, 0, stream>>>(xpack, degi, rowstart, part, d_out, flags,
                                     w1l, b1, w1r, w2l, b2, w2r, head_w,
                                     hl, st, ypart, N);
    k_layer2<<<gb2, 256, 0, stream>>>(degi, rowstart, part, hl, st, ypart,
                                      d_out, flags, head_w, head_b, N);
}

// Round 9
// 301.333 us; speedup vs baseline: 31.2456x; 1.0126x over previous
//
#include <hip/hip_runtime.h>
#include <hip/hip_bf16.h>

#define MF 24      // input feature dim
#define HIDF 32    // hidden dim
#define OUTF 16    // emb dim
#define ZDIM 88    // 3*MF + OUTF
#define NPB 8      // nodes per 256-thread block in k_layer1 (32 lanes/node)
#define NPB2 32    // nodes per 256-thread block in k_layer2 (8 lanes/node)
#define SW1 28     // LDS stride for w1 (16B-aligned rows, b128-able)
#define SW2 36     // LDS stride for w2 (16B-aligned rows, b128-able)

#define NB 512     // dest-range buckets for CSR counting sort
#define EB 16384   // edges per partition block (64 per thread)
#define CAP 8192   // LDS staging capacity (edges) in k_csrC

union bf16x8 {
    float4 v;
    __hip_bfloat16 h[8];
};
union bf16x2u {
    unsigned int u;
    __hip_bfloat16 h[2];
};

// flagged scalar load: element i of a float array that is either bf16 or fp32
__device__ __forceinline__ float ldw(const void* p, size_t i, bool bf16) {
    return bf16 ? __bfloat162float(((const __hip_bfloat16*)p)[i])
                : ((const float*)p)[i];
}

// ---------------------------------------------------------------------------
// Detect input dtypes at runtime (deterministic, runs every launch).
// flags[0]=1 if float arrays are bf16-packed; flags[1]=1 if edge ints are i64.
// ---------------------------------------------------------------------------
__global__ __launch_bounds__(64) void k_detect(const unsigned int* __restrict__ xw,
                                               const unsigned int* __restrict__ ew,
                                               int* __restrict__ flags) {
    if (blockIdx.x == 0 && threadIdx.x == 0) {
        int bf = 0;
        for (int k = 0; k < 64; ++k)
            if ((xw[k] & 0xFFFFu) == 0x3F80u) bf = 1;
        int zc = 0;
        for (int k = 0; k < 64; ++k)
            if (ew[2 * k + 1] == 0u) zc++;
        flags[0] = bf;
        flags[1] = (zc >= 32) ? 1 : 0;
    }
}

// ---------------------------------------------------------------------------
// Pack binary x rows (24 wide) into u32 bitmasks. x values are exactly {0,1}.
// ---------------------------------------------------------------------------
__global__ __launch_bounds__(256) void k_pack(const void* __restrict__ x,
                                              const int* __restrict__ flags,
                                              unsigned int* __restrict__ xpack, int N) {
    const bool bf16 = flags[0] != 0;
    int n = blockIdx.x * 256 + threadIdx.x;
    if (n >= N) return;
    unsigned int m = 0;
    if (bf16) {
        const float4* xr = reinterpret_cast<const float4*>(
            (const __hip_bfloat16*)x + (size_t)n * MF);
        bf16x8 u;
#pragma unroll
        for (int q = 0; q < 3; ++q) {
            u.v = xr[q];
#pragma unroll
            for (int i = 0; i < 8; ++i)
                if (__bfloat162float(u.h[i]) != 0.f) m |= 1u << (q * 8 + i);
        }
    } else {
        const float* xr = (const float*)x + (size_t)n * MF;
#pragma unroll
        for (int k = 0; k < MF; ++k)
            if (xr[k] != 0.f) m |= 1u << k;
    }
    xpack[n] = m;
}

// ---------------------------------------------------------------------------
// CSR pass A: per-block LDS histogram over NB dest-range buckets.
// ---------------------------------------------------------------------------
__global__ __launch_bounds__(256) void k_histA(const int* __restrict__ ei,
                                               const int* __restrict__ flags,
                                               int* __restrict__ counts,
                                               int nE, int N, int W) {
    __shared__ int hist[NB];
    for (int i = threadIdx.x; i < NB; i += 256) hist[i] = 0;
    __syncthreads();
    const bool i64 = flags[1] != 0;
    size_t base = (size_t)blockIdx.x * EB;
    for (int i = threadIdx.x; i < EB; i += 256) {
        size_t e = base + i;
        if (e < (size_t)nE) {
            int c = i64 ? ei[2 * ((size_t)nE + e)] : ei[(size_t)nE + e];
            if ((unsigned)c < (unsigned)N) atomicAdd(&hist[c / W], 1);
        }
    }
    __syncthreads();
    for (int i = threadIdx.x; i < NB; i += 256)
        counts[(size_t)blockIdx.x * NB + i] = hist[i];
}

// ---------------------------------------------------------------------------
// CSR scan 1: per-bucket column scan over blocks (one block per bucket).
// ---------------------------------------------------------------------------
__global__ __launch_bounds__(1024) void k_colscan(int* __restrict__ counts,
                                                  int* __restrict__ colSum, int nBlk) {
    __shared__ int s[1024];
    int b = blockIdx.x, t = threadIdx.x;
    int v = (t < nBlk) ? counts[(size_t)t * NB + b] : 0;
    s[t] = v;
    __syncthreads();
    for (int off = 1; off < 1024; off <<= 1) {
        int y = (t >= off) ? s[t - off] : 0;
        __syncthreads();
        s[t] += y;
        __syncthreads();
    }
    if (t < nBlk) counts[(size_t)t * NB + b] = s[t] - v;
    if (t == 1023) colSum[b] = s[1023];
}

// ---------------------------------------------------------------------------
// CSR scan 2: exclusive scan of colSum -> bucketStart[0..NB].
// ---------------------------------------------------------------------------
__global__ __launch_bounds__(1024) void k_bstart(const int* __restrict__ colSum,
                                                 int* __restrict__ bucketStart) {
    __shared__ int s[1024];
    int t = threadIdx.x;
    int v = (t < NB) ? colSum[t] : 0;
    s[t] = v;
    __syncthreads();
    for (int off = 1; off < 1024; off <<= 1) {
        int y = (t >= off) ? s[t - off] : 0;
        __syncthreads();
        s[t] += y;
        __syncthreads();
    }
    if (t < NB) bucketStart[t] = s[t] - v;
    if (t == NB - 1) bucketStart[NB] = s[t];
}

// ---------------------------------------------------------------------------
// CSR pass B: deterministic scatter into bucket-major order. Only LDS atomics.
// part[pos] = src | (local_dest << 20). src < 2^17 (N<=131072), local < 256.
// ---------------------------------------------------------------------------
__global__ __launch_bounds__(256) void k_scatB(const int* __restrict__ ei,
                                               const int* __restrict__ flags,
                                               const int* __restrict__ counts,
                                               const int* __restrict__ bucketStart,
                                               unsigned int* __restrict__ part,
                                               int nE, int N, int W) {
    __shared__ int base[NB];
    __shared__ int cnt[NB];
    for (int i = threadIdx.x; i < NB; i += 256) {
        base[i] = bucketStart[i] + counts[(size_t)blockIdx.x * NB + i];
        cnt[i] = 0;
    }
    __syncthreads();
    const bool i64 = flags[1] != 0;
    size_t eb = (size_t)blockIdx.x * EB;
    for (int i = threadIdx.x; i < EB; i += 256) {
        size_t e = eb + i;
        if (e < (size_t)nE) {
            int r = i64 ? ei[2 * e] : ei[e];
            int c = i64 ? ei[2 * ((size_t)nE + e)] : ei[(size_t)nE + e];
            if ((unsigned)c < (unsigned)N) {
                int b = c / W;
                int ld = c - b * W;
                unsigned rr = ((unsigned)r < (unsigned)N) ? (unsigned)r : 0u;
                int pos = base[b] + atomicAdd(&cnt[b], 1);
                part[pos] = rr | ((unsigned)ld << 20);
            }
        }
    }
}

// ---------------------------------------------------------------------------
// CSR pass C: one block per bucket; LDS counting sort; writes degi/rowstart.
// ---------------------------------------------------------------------------
__global__ __launch_bounds__(256) void k_csrC(const int* __restrict__ bucketStart,
                                              unsigned int* __restrict__ part,
                                              int* __restrict__ degi,
                                              int* __restrict__ rowstart,
                                              int N, int W) {
    __shared__ unsigned int stage[CAP];
    __shared__ unsigned int sorted[CAP];
    __shared__ int hist[256];
    __shared__ int sc[256];
    __shared__ int cur[256];
    int b = blockIdx.x, t = threadIdx.x;
    int start = bucketStart[b];
    int bs = bucketStart[b + 1] - start;
    int node = b * W + t;

    hist[t] = 0;
    __syncthreads();

    if (bs > CAP) {  // statistically impossible for this graph; stay memory-safe
        if (t < W && node < N) { degi[node] = 0; rowstart[node] = start; }
        return;
    }

    for (int i = t; i < bs; i += 256) {
        unsigned int v = part[start + i];
        stage[i] = v;
        atomicAdd(&hist[v >> 20], 1);
    }
    __syncthreads();

    int v = hist[t];
    sc[t] = v;
    __syncthreads();
    for (int off = 1; off < 256; off <<= 1) {
        int y = (t >= off) ? sc[t - off] : 0;
        __syncthreads();
        sc[t] += y;
        __syncthreads();
    }
    int excl = sc[t] - v;
    if (t < W && node < N) {
        degi[node] = v;
        rowstart[node] = start + excl;
    }
    cur[t] = excl;
    __syncthreads();

    for (int i = t; i < bs; i += 256) {
        unsigned int v2 = stage[i];
        int pos = atomicAdd(&cur[v2 >> 20], 1);
        sorted[pos] = v2 & 0xFFFFFu;
    }
    __syncthreads();
    for (int i = t; i < bs; i += 256) part[start + i] = sorted[i];
}

// per-sub-block ballot counting. Ballot result is wave-uniform -> popcounts
// are SALU; delivery to lane b is a literal compare + cndmask pick.
// lanes 24..31 (and 56..63) never match b_ and keep 0.
#define PROC_MASK(mreg)                                                 \
    {                                                                   \
        int t_ = 0;                                                     \
        _Pragma("unroll")                                               \
        for (int b_ = 0; b_ < MF; ++b_) {                               \
            unsigned long long bal_ = __ballot((mreg >> b_) & 1u);      \
            int lo_ = __popc((unsigned int)bal_);                       \
            int hi_ = __popc((unsigned int)(bal_ >> 32));               \
            int pick_ = hiHalf ? hi_ : lo_;                             \
            t_ += (lane == b_) ? pick_ : 0;                             \
        }                                                               \
        cnt += t_;                                                      \
    }

// ---------------------------------------------------------------------------
// Layer 1 + projection: 32 lanes per node, edge-parallel ballot gather with
// 4 prefetched sub-blocks per round and SALU popcounts. Dense phase uses
// b128 LDS broadcasts instead of shfl chains.
// ---------------------------------------------------------------------------
__global__ __launch_bounds__(256) void k_layer1(
    const unsigned int* __restrict__ xpack, const int* __restrict__ degi,
    const int* __restrict__ rowstart, const unsigned int* __restrict__ srcs,
    void* __restrict__ out, const int* __restrict__ flags,
    const void* __restrict__ w1l, const void* __restrict__ b1,
    const void* __restrict__ w1r, const void* __restrict__ w2l,
    const void* __restrict__ b2, const void* __restrict__ w2r,
    const void* __restrict__ head_w,
    __hip_bfloat16* __restrict__ hl, __hip_bfloat16* __restrict__ st,
    float* __restrict__ ypart, int N) {
    const bool bf16 = flags[0] != 0;
    __shared__ float swl[HIDF * SW1];
    __shared__ float swr[HIDF * SW1];
    __shared__ float sb[HIDF];
    __shared__ float s2l[OUTF * SW2];
    __shared__ float s2r[OUTF * SW2];
    __shared__ float sb2[OUTF];
    __shared__ float shw[3 * MF];
    __shared__ float fs[NPB][MF];     // 96B rows, 16B-aligned
    __shared__ float hs[NPB][HIDF];   // 128B rows
    for (int i = threadIdx.x; i < HIDF * MF; i += 256) {
        int j = i / MF, k = i - j * MF;
        swl[j * SW1 + k] = ldw(w1l, i, bf16);
        swr[j * SW1 + k] = ldw(w1r, i, bf16);
    }
    for (int i = threadIdx.x; i < OUTF * HIDF; i += 256) {
        int o = i >> 5, j = i & 31;
        s2l[o * SW2 + j] = ldw(w2l, i, bf16);
        s2r[o * SW2 + j] = ldw(w2r, i, bf16);
    }
    if (threadIdx.x < HIDF) sb[threadIdx.x] = ldw(b1, threadIdx.x, bf16);
    if (threadIdx.x < OUTF) sb2[threadIdx.x] = ldw(b2, threadIdx.x, bf16);
    if (threadIdx.x < 3 * MF) shw[threadIdx.x] = ldw(head_w, threadIdx.x, bf16);
    __syncthreads();

    int lane = threadIdx.x & 31;
    int wg = threadIdx.x >> 5;
    const bool hiHalf = (threadIdx.x & 32) != 0;
    int node = blockIdx.x * NPB + wg;
    bool valid = node < N;

    int dg = 0, p0 = 0;
    unsigned int xpn = 0;
    if (valid) {
        dg = degi[node];
        p0 = rowstart[node];
        xpn = xpack[node];
    }

    // wave-uniform max degree -> scalar loop/branch structure
    int dgmax = dg;
#pragma unroll
    for (int off = 32; off > 0; off >>= 1)
        dgmax = max(dgmax, __shfl_xor(dgmax, off, 64));

    int cnt = 0;
    for (int base = 0; base < dgmax; base += 128) {
        unsigned int m0 = 0, m1 = 0, m2 = 0, m3 = 0;
        int e0 = base + lane;
        if (e0 < dg) m0 = xpack[srcs[p0 + e0]];
        if (e0 + 32 < dg) m1 = xpack[srcs[p0 + e0 + 32]];
        if (e0 + 64 < dg) m2 = xpack[srcs[p0 + e0 + 64]];
        if (e0 + 96 < dg) m3 = xpack[srcs[p0 + e0 + 96]];
        PROC_MASK(m0);
        if (base + 32 < dgmax) PROC_MASK(m1);
        if (base + 64 < dgmax) PROC_MASK(m2);
        if (base + 96 < dgmax) PROC_MASK(m3);
    }

    float inv = 1.f / fmaxf((float)dg, 1.f);
    float fv = (float)cnt * inv;          // lanes >= 24: cnt==0 -> fv==0
    float xv = (float)((xpn >> lane) & 1);

    float pc = 0.f;
    if (valid && lane < MF) {
        if (bf16) {
            __hip_bfloat16* z = (__hip_bfloat16*)out + N + (size_t)node * ZDIM;
            z[lane] = __float2bfloat16(xv);
            z[MF + lane] = __float2bfloat16(fv);
            z[2 * MF + lane] = __float2bfloat16(xv * fv);
        } else {
            float* z = (float*)out + N + (size_t)node * ZDIM;
            z[lane] = xv;
            z[MF + lane] = fv;
            z[2 * MF + lane] = xv * fv;
        }
        pc = xv * shw[lane] + fv * shw[MF + lane] + xv * fv * shw[2 * MF + lane];
    }

    // stage fv once; same-wave LDS ordering, no barrier needed
    if (lane < MF) fs[wg][lane] = fv;

    float fvk[MF];
    {
        const float4* fp = (const float4*)fs[wg];   // broadcast b128 reads
#pragma unroll
        for (int q = 0; q < 6; ++q) {
            float4 f4 = fp[q];
            fvk[q * 4 + 0] = f4.x; fvk[q * 4 + 1] = f4.y;
            fvk[q * 4 + 2] = f4.z; fvk[q * 4 + 3] = f4.w;
        }
    }
    float wlv[MF], wrv[MF];
    {
        const float4* wl4 = (const float4*)(swl + lane * SW1);
        const float4* wr4 = (const float4*)(swr + lane * SW1);
#pragma unroll
        for (int q = 0; q < 6; ++q) {
            float4 a = wl4[q], b = wr4[q];
            wlv[q * 4 + 0] = a.x; wlv[q * 4 + 1] = a.y;
            wlv[q * 4 + 2] = a.z; wlv[q * 4 + 3] = a.w;
            wrv[q * 4 + 0] = b.x; wrv[q * 4 + 1] = b.y;
            wrv[q * 4 + 2] = b.z; wrv[q * 4 + 3] = b.w;
        }
    }
    float acc = sb[lane];
#pragma unroll
    for (int k = 0; k < MF; ++k) {
        acc = fmaf(fvk[k], wlv[k], acc);
        acc += ((xpn >> k) & 1u) ? wrv[k] : 0.f;
    }
    hs[wg][lane] = fmaxf(acc, 0.f);

    // reduce head partial across the 32-lane group
#pragma unroll
    for (int off = 16; off > 0; off >>= 1) pc += __shfl_down(pc, off, 32);

    // projection: half 0 -> hl[o] = h.W2l[o], half 1 -> st[o] = b2[o] + h.W2r[o]
    int o = lane & 15;
    int half = lane >> 4;
    const float4* wrow4 = (const float4*)((half ? s2r : s2l) + o * SW2);
    const float4* hp4 = (const float4*)hs[wg];
    float d = 0.f;
#pragma unroll
    for (int q = 0; q < 8; ++q) {
        float4 hq = hp4[q], wq = wrow4[q];
        d += hq.x * wq.x + hq.y * wq.y + hq.z * wq.z + hq.w * wq.w;
    }
    if (valid) {
        if (half == 0) hl[(size_t)node * OUTF + o] = __float2bfloat16(d);
        else st[(size_t)node * OUTF + o] = __float2bfloat16(d + sb2[o]);
        if (lane == 0) ypart[node] = pc;
    }
}

// ---------------------------------------------------------------------------
// Layer 2 (projected gather + head): 8 lanes per node, 2 features per lane
// via bf16x2 pair loads. emb = relu(mean(hl[src]) + st); z[72:88);
// yhat = ypart + emb.w_head + b.
// ---------------------------------------------------------------------------
__global__ __launch_bounds__(256) void k_layer2(
    const int* __restrict__ degi, const int* __restrict__ rowstart,
    const unsigned int* __restrict__ srcs, const __hip_bfloat16* __restrict__ hl,
    const __hip_bfloat16* __restrict__ st, const float* __restrict__ ypart,
    void* __restrict__ out, const int* __restrict__ flags,
    const void* __restrict__ head_w, const void* __restrict__ head_b, int N) {
    const bool bf16 = flags[0] != 0;
    __shared__ float shw2[OUTF];
    __shared__ float shb;
    if (threadIdx.x < OUTF) shw2[threadIdx.x] = ldw(head_w, 3 * MF + threadIdx.x, bf16);
    if (threadIdx.x == 0) shb = ldw(head_b, 0, bf16);
    __syncthreads();

    int lane = threadIdx.x & 7;
    int g = threadIdx.x >> 3;
    int node = blockIdx.x * NPB2 + g;
    bool valid = node < N;

    int dg = 0, p0 = 0;
    if (valid) {
        dg = degi[node];
        p0 = rowstart[node];
    }
    const unsigned int* hlw = (const unsigned int*)hl;
    float s0 = 0.f, s1 = 0.f;
    int e = 0;
    for (; e + 4 <= dg; e += 4) {
        int a = srcs[p0 + e], b = srcs[p0 + e + 1];
        int c = srcs[p0 + e + 2], d = srcs[p0 + e + 3];
        bf16x2u ua, ub, uc, ud;
        ua.u = hlw[(size_t)a * 8 + lane];
        ub.u = hlw[(size_t)b * 8 + lane];
        uc.u = hlw[(size_t)c * 8 + lane];
        ud.u = hlw[(size_t)d * 8 + lane];
        s0 += (__bfloat162float(ua.h[0]) + __bfloat162float(ub.h[0])) +
              (__bfloat162float(uc.h[0]) + __bfloat162float(ud.h[0]));
        s1 += (__bfloat162float(ua.h[1]) + __bfloat162float(ub.h[1])) +
              (__bfloat162float(uc.h[1]) + __bfloat162float(ud.h[1]));
    }
    for (; e < dg; ++e) {
        bf16x2u ua;
        ua.u = hlw[(size_t)srcs[p0 + e] * 8 + lane];
        s0 += __bfloat162float(ua.h[0]);
        s1 += __bfloat162float(ua.h[1]);
    }

    float emb0 = 0.f, emb1 = 0.f;
    if (valid) {
        float inv = 1.f / fmaxf((float)dg, 1.f);
        bf16x2u us;
        us.u = ((const unsigned int*)st)[(size_t)node * 8 + lane];
        emb0 = fmaxf(s0 * inv + __bfloat162float(us.h[0]), 0.f);
        emb1 = fmaxf(s1 * inv + __bfloat162float(us.h[1]), 0.f);
        if (bf16) {
            __hip_bfloat16* z = (__hip_bfloat16*)out + N + (size_t)node * ZDIM;
            z[3 * MF + 2 * lane] = __float2bfloat16(emb0);
            z[3 * MF + 2 * lane + 1] = __float2bfloat16(emb1);
        } else {
            float* z = (float*)out + N + (size_t)node * ZDIM;
            z[3 * MF + 2 * lane] = emb0;
            z[3 * MF + 2 * lane + 1] = emb1;
        }
    }
    float part = emb0 * shw2[2 * lane] + emb1 * shw2[2 * lane + 1];
#pragma unroll
    for (int off = 4; off > 0; off >>= 1) part += __shfl_down(part, off, 8);
    if (valid && lane == 0) {
        float y = ypart[node] + part + shb;
        if (bf16) ((__hip_bfloat16*)out)[node] = __float2bfloat16(y);
        else ((float*)out)[node] = y;
    }
}

extern "C" void kernel_launch(void* const* d_in, const int* in_sizes, int n_in,
                              void* d_out, int out_size, void* d_ws, size_t ws_size,
                              hipStream_t stream) {
    const void* x = d_in[0];
    const int* ei = (const int*)d_in[1];
    const void* w1l = d_in[2];
    const void* b1 = d_in[3];
    const void* w1r = d_in[4];
    const void* w2l = d_in[5];
    const void* b2 = d_in[6];
    const void* w2r = d_in[7];
    const void* head_w = d_in[8];
    const void* head_b = d_in[9];

    const int N = in_sizes[0] / MF;
    const int nE = in_sizes[1] / 2;
    const int W = (N + NB - 1) / NB;          // bucket width (dest ids per bucket)
    const int nBlkA = (nE + EB - 1) / EB;     // partition blocks

    // structural limits (hold for N=100k, nE=3.2M); ypart aliases counts
    if (N > NB * 256 || N > 131072 || nBlkA > 1024 ||
        (size_t)nBlkA * NB < (size_t)N) return;

    // workspace layout:
    // flags(256B) | bucketStart[NB+1] | colSum[NB] | degi[N] | rowstart[N]
    // | counts[nBlkA*NB] (reused as ypart[N] f32 after k_scatB)
    // | part[nE] u32 (becomes final CSR srcs, in place)
    // | xpack[N] | hl[N*16] bf16 | st[N*16] bf16
    int* flags = (int*)d_ws;
    int* bucketStart = (int*)((char*)d_ws + 256);
    int* colSum = bucketStart + (NB + 1);
    int* degi = colSum + NB;
    int* rowstart = degi + N;
    int* counts = rowstart + N;
    unsigned int* part = (unsigned int*)(counts + (size_t)nBlkA * NB);
    unsigned int* xpack = part + nE;
    __hip_bfloat16* hl = (__hip_bfloat16*)(xpack + N);
    __hip_bfloat16* st = hl + (size_t)N * OUTF;
    float* ypart = (float*)counts;  // counts is dead after k_scatB

    const size_t need = 256 +
        ((size_t)(NB + 1) + NB + 2 * (size_t)N + (size_t)nBlkA * NB +
         (size_t)nE + (size_t)N) * 4 + (size_t)N * OUTF * 2 * 2;
    if (ws_size < need) return;  // visible failure (zero output)

    const int nB = (N + 255) / 256;
    const int gb = (N + NPB - 1) / NPB;
    const int gb2 = (N + NPB2 - 1) / NPB2;
    k_detect<<<1, 64, 0, stream>>>((const unsigned int*)x, (const unsigned int*)ei, flags);
    k_pack<<<nB, 256, 0, stream>>>(x, flags, xpack, N);
    k_histA<<<nBlkA, 256, 0, stream>>>(ei, flags, counts, nE, N, W);
    k_colscan<<<NB, 1024, 0, stream>>>(counts, colSum, nBlkA);
    k_bstart<<<1, 1024, 0, stream>>>(colSum, bucketStart);
    k_scatB<<<nBlkA, 256, 0, stream>>>(ei, flags, counts, bucketStart, part, nE, N, W);
    k_csrC<<<NB, 256, 0, stream>>>(bucketStart, part, degi, rowstart, N, W);
    k_layer1<<<gb, 256, 0, stream>>>(xpack, degi, rowstart, part, d_out, flags,
                                     w1l, b1, w1r, w2l, b2, w2r, head_w,
                                     hl, st, ypart, N);
    k_layer2<<<gb2, 256, 0, stream>>>(degi, rowstart, part, hl, st, ypart,
                                      d_out, flags, head_w, head_b, N);
}